// Round 1
// baseline (2105.666 us; speedup 1.0000x reference)
//
#include <hip/hip_runtime.h>
#include <stdint.h>

namespace {

constexpr int B = 8;
constexpr int H = 1024;
constexpr int W = 1024;
constexpr int TOPK = 4096;
constexpr int TILE = 32;
constexpr int HALO = 2;
constexpr int LT = TILE + 2 * HALO;  // 36
constexpr int CAND_CAP = 131072;     // per batch
constexpr int SEL_CAP = 8192;        // per batch (64 KB LDS sort)
constexpr int HIST_SHIFT = 15;       // bucket = score_bits >> 15
constexpr int HIST_SIZE = 1 << 17;   // 131072 buckets
constexpr int CHUNK = HIST_SIZE / 1024;  // 128

// workspace layout (bytes)
constexpr size_t OFF_MASK0 = 0;                               // B*H*W bytes = 8 MiB
constexpr size_t OFF_MASK1 = (size_t)8 << 20;                 // 8 MiB
constexpr size_t OFF_SUPP  = (size_t)16 << 20;                // 8 MiB (supp1 then supp2)
constexpr size_t OFF_HIST  = (size_t)24 << 20;                // B*HIST_SIZE*4 = 4 MiB
constexpr size_t OFF_CNT   = (size_t)28 << 20;                // counters, 4 KiB
constexpr size_t OFF_SEL   = OFF_CNT + 4096;                  // B*SEL_CAP*8 = 512 KiB
constexpr size_t OFF_TOPK  = OFF_SEL + (size_t)B * SEL_CAP * 8; // B*TOPK*8 = 256 KiB
constexpr size_t OFF_CAND  = 0;  // reuse mask0 region: B*CAND_CAP*8 = 8 MiB exactly
// total ws needed ~= 28.75 MiB

__device__ __forceinline__ int ldsidx(int ly, int lx) { return ly * LT + lx; }

// P1: mask0 = (scores == maxpool5x5(scores))   [-inf padding]
__global__ void __launch_bounds__(1024) k_mask0(const float* __restrict__ scores,
                                                unsigned char* __restrict__ mask0) {
  __shared__ float sc[LT * LT];
  const int b = blockIdx.z;
  const int x0 = blockIdx.x * TILE - HALO;
  const int y0 = blockIdx.y * TILE - HALO;
  const float* img = scores + (size_t)b * H * W;
  const int tid = threadIdx.y * TILE + threadIdx.x;
  for (int i = tid; i < LT * LT; i += TILE * TILE) {
    int ly = i / LT, lx = i % LT;
    int gy = y0 + ly, gx = x0 + lx;
    float v = -INFINITY;
    if (gx >= 0 && gx < W && gy >= 0 && gy < H) v = img[gy * W + gx];
    sc[i] = v;
  }
  __syncthreads();
  const int lx = threadIdx.x + HALO, ly = threadIdx.y + HALO;
  float c = sc[ldsidx(ly, lx)];
  float m = -INFINITY;
#pragma unroll
  for (int dy = -2; dy <= 2; ++dy)
#pragma unroll
    for (int dx = -2; dx <= 2; ++dx) m = fmaxf(m, sc[ldsidx(ly + dy, lx + dx)]);
  int gy = y0 + ly, gx = x0 + lx;
  mask0[(size_t)b * H * W + gy * W + gx] = (c == m) ? 1 : 0;
}

// dilate: supp = any(mask in 5x5, in-bounds)  == (maxpool(mask.astype(f32)) > 0)
__global__ void __launch_bounds__(1024) k_dilate(const unsigned char* __restrict__ maskIn,
                                                 unsigned char* __restrict__ suppOut) {
  __shared__ unsigned char mk[LT * LT];
  const int b = blockIdx.z;
  const int x0 = blockIdx.x * TILE - HALO;
  const int y0 = blockIdx.y * TILE - HALO;
  const unsigned char* img = maskIn + (size_t)b * H * W;
  const int tid = threadIdx.y * TILE + threadIdx.x;
  for (int i = tid; i < LT * LT; i += TILE * TILE) {
    int ly = i / LT, lx = i % LT;
    int gy = y0 + ly, gx = x0 + lx;
    unsigned char v = 0;
    if (gx >= 0 && gx < W && gy >= 0 && gy < H) v = img[gy * W + gx];
    mk[i] = v;
  }
  __syncthreads();
  const int lx = threadIdx.x + HALO, ly = threadIdx.y + HALO;
  unsigned char any = 0;
#pragma unroll
  for (int dy = -2; dy <= 2; ++dy)
#pragma unroll
    for (int dx = -2; dx <= 2; ++dx) any |= mk[ldsidx(ly + dy, lx + dx)];
  int gy = y0 + ly, gx = x0 + lx;
  suppOut[(size_t)b * H * W + gy * W + gx] = any ? 1 : 0;
}

// refine pass: supp_scores = supp ? 0 : scores (outside image = -inf)
// new_max = (supp_scores == maxpool(supp_scores)); maskOut = maskIn | (new_max & !supp)
__global__ void __launch_bounds__(1024) k_mask_update(const float* __restrict__ scores,
                                                      const unsigned char* __restrict__ supp,
                                                      const unsigned char* __restrict__ maskIn,
                                                      unsigned char* __restrict__ maskOut) {
  __shared__ float ss[LT * LT];
  const int b = blockIdx.z;
  const int x0 = blockIdx.x * TILE - HALO;
  const int y0 = blockIdx.y * TILE - HALO;
  const size_t base = (size_t)b * H * W;
  const int tid = threadIdx.y * TILE + threadIdx.x;
  for (int i = tid; i < LT * LT; i += TILE * TILE) {
    int ly = i / LT, lx = i % LT;
    int gy = y0 + ly, gx = x0 + lx;
    float v = -INFINITY;
    if (gx >= 0 && gx < W && gy >= 0 && gy < H) {
      size_t g = base + (size_t)gy * W + gx;
      v = supp[g] ? 0.0f : scores[g];
    }
    ss[i] = v;
  }
  __syncthreads();
  const int lx = threadIdx.x + HALO, ly = threadIdx.y + HALO;
  float c = ss[ldsidx(ly, lx)];
  float m = -INFINITY;
#pragma unroll
  for (int dy = -2; dy <= 2; ++dy)
#pragma unroll
    for (int dx = -2; dx <= 2; ++dx) m = fmaxf(m, ss[ldsidx(ly + dy, lx + dx)]);
  int gy = y0 + ly, gx = x0 + lx;
  size_t g = base + (size_t)gy * W + gx;
  bool sp = supp[g] != 0;
  bool newmax = (c == m);
  maskOut[g] = (maskIn[g] || (newmax && !sp)) ? 1 : 0;
}

// final pass: mask2 = mask1 | (new_max2 & !supp2); emit candidate keys + histogram
__global__ void __launch_bounds__(1024) k_emit(const float* __restrict__ scores,
                                               const unsigned char* __restrict__ supp,
                                               const unsigned char* __restrict__ maskIn,
                                               uint64_t* __restrict__ cand,
                                               uint32_t* __restrict__ cand_count,
                                               uint32_t* __restrict__ hist) {
  __shared__ float ss[LT * LT];
  const int b = blockIdx.z;
  const int x0 = blockIdx.x * TILE - HALO;
  const int y0 = blockIdx.y * TILE - HALO;
  const size_t base = (size_t)b * H * W;
  const int tid = threadIdx.y * TILE + threadIdx.x;
  for (int i = tid; i < LT * LT; i += TILE * TILE) {
    int ly = i / LT, lx = i % LT;
    int gy = y0 + ly, gx = x0 + lx;
    float v = -INFINITY;
    if (gx >= 0 && gx < W && gy >= 0 && gy < H) {
      size_t g = base + (size_t)gy * W + gx;
      v = supp[g] ? 0.0f : scores[g];
    }
    ss[i] = v;
  }
  __syncthreads();
  const int lx = threadIdx.x + HALO, ly = threadIdx.y + HALO;
  float c = ss[ldsidx(ly, lx)];
  float m = -INFINITY;
#pragma unroll
  for (int dy = -2; dy <= 2; ++dy)
#pragma unroll
    for (int dx = -2; dx <= 2; ++dx) m = fmaxf(m, ss[ldsidx(ly + dy, lx + dx)]);
  int gy = y0 + ly, gx = x0 + lx;
  size_t g = base + (size_t)gy * W + gx;
  bool sp = supp[g] != 0;
  bool mask2 = maskIn[g] || ((c == m) && !sp);
  bool border = (gy < 2) || (gy >= H - 2) || (gx < 2) || (gx >= W - 2);
  if (mask2 && !border) {
    float s = scores[g];  // original score (center may be suppressed in ss)
    if (s > 0.0f) {
      uint32_t bits = __float_as_uint(s);
      uint32_t flat = (uint32_t)(gy * W + gx);
      uint64_t key = ((uint64_t)bits << 32) | (uint64_t)(0xFFFFFFFFu - flat);
      uint32_t pos = atomicAdd(&cand_count[b], 1u);
      if (pos < (uint32_t)CAND_CAP) cand[(size_t)b * CAND_CAP + pos] = key;
      atomicAdd(&hist[(size_t)b * HIST_SIZE + (bits >> HIST_SHIFT)], 1u);
    }
  }
}

// per-batch: find largest bucket T with count(bits>>15 >= T) >= TOPK
__global__ void __launch_bounds__(1024) k_thresh(const uint32_t* __restrict__ hist,
                                                 uint32_t* __restrict__ thr) {
  __shared__ uint32_t suf[1024];
  __shared__ uint32_t sub[CHUNK];
  __shared__ uint32_t sh_chunk;
  __shared__ uint32_t sh_T;
  const int b = blockIdx.x;
  const uint32_t* h = hist + (size_t)b * HIST_SIZE;
  const int t = threadIdx.x;
  uint32_t s = 0;
  const uint32_t* hc = h + (size_t)t * CHUNK;
  for (int i = 0; i < CHUNK; ++i) s += hc[i];
  suf[t] = s;
  if (t == 0) { sh_chunk = 0xFFFFFFFFu; sh_T = 0; }
  __syncthreads();
  for (int d = 1; d < 1024; d <<= 1) {
    uint32_t v = (t + d < 1024) ? suf[t + d] : 0u;
    __syncthreads();
    suf[t] += v;
    __syncthreads();
  }
  {
    uint32_t mine = suf[t];
    uint32_t nxt = (t + 1 < 1024) ? suf[t + 1] : 0u;
    if (mine >= (uint32_t)TOPK && nxt < (uint32_t)TOPK) sh_chunk = (uint32_t)t;
  }
  __syncthreads();
  uint32_t c = sh_chunk;
  if (c == 0xFFFFFFFFu) {  // fewer than TOPK candidates total: select everything
    if (t == 0) thr[b] = 0;
    return;
  }
  uint32_t base_above = (c + 1 < 1024) ? suf[c + 1] : 0u;
  if (t < CHUNK) sub[t] = h[(size_t)c * CHUNK + t];
  __syncthreads();
  for (int d = 1; d < CHUNK; d <<= 1) {
    uint32_t v = 0;
    if (t < CHUNK && t + d < CHUNK) v = sub[t + d];
    __syncthreads();
    if (t < CHUNK) sub[t] += v;
    __syncthreads();
  }
  if (t < CHUNK) {
    uint32_t mine = base_above + sub[t];
    uint32_t nxt = (t + 1 < CHUNK) ? base_above + sub[t + 1] : base_above;
    if (mine >= (uint32_t)TOPK && nxt < (uint32_t)TOPK) sh_T = c * CHUNK + (uint32_t)t;
  }
  __syncthreads();
  if (t == 0) thr[b] = sh_T;
}

__global__ void k_compact(const uint64_t* __restrict__ cand,
                          const uint32_t* __restrict__ cand_count,
                          const uint32_t* __restrict__ thr,
                          uint64_t* __restrict__ sel,
                          uint32_t* __restrict__ sel_count) {
  const int b = blockIdx.y;
  uint32_t n = cand_count[b];
  if (n > (uint32_t)CAND_CAP) n = CAND_CAP;
  uint32_t i = blockIdx.x * blockDim.x + threadIdx.x;
  if (i >= n) return;
  uint64_t key = cand[(size_t)b * CAND_CAP + i];
  uint32_t bucket = (uint32_t)(key >> (32 + HIST_SHIFT));
  if (bucket >= thr[b]) {
    uint32_t pos = atomicAdd(&sel_count[b], 1u);
    if (pos < (uint32_t)SEL_CAP) sel[(size_t)b * SEL_CAP + pos] = key;
  }
}

// one block per batch: bitonic sort SEL_CAP keys descending, write top TOPK
__global__ void __launch_bounds__(1024) k_sort(const uint64_t* __restrict__ sel,
                                               const uint32_t* __restrict__ sel_count,
                                               uint64_t* __restrict__ topk) {
  __shared__ uint64_t keys[SEL_CAP];  // 64 KiB
  const int b = blockIdx.x;
  uint32_t n = sel_count[b];
  if (n > (uint32_t)SEL_CAP) n = SEL_CAP;
  for (int i = threadIdx.x; i < SEL_CAP; i += 1024)
    keys[i] = ((uint32_t)i < n) ? sel[(size_t)b * SEL_CAP + i] : 0ull;
  __syncthreads();
  for (unsigned k = 2; k <= (unsigned)SEL_CAP; k <<= 1) {
    for (unsigned j = k >> 1; j > 0; j >>= 1) {
      for (unsigned t = threadIdx.x; t < (unsigned)SEL_CAP; t += 1024) {
        unsigned p = t ^ j;
        if (p > t) {
          uint64_t a = keys[t], c = keys[p];
          bool desc = ((t & k) == 0);
          if ((a < c) == desc) { keys[t] = c; keys[p] = a; }
        }
      }
      __syncthreads();
    }
  }
  for (int i = threadIdx.x; i < TOPK; i += 1024)
    topk[(size_t)b * TOPK + i] = keys[i];
}

// per-keypoint refinement: softargmax residual, dispersity, bilinear score
__global__ void k_refine(const float* __restrict__ scores,
                         const uint64_t* __restrict__ topk,
                         float* __restrict__ out) {
  int gid = blockIdx.x * blockDim.x + threadIdx.x;
  if (gid >= B * TOPK) return;
  const int b = gid / TOPK;
  const int k = gid % TOPK;
  uint64_t key = topk[(size_t)b * TOPK + k];
  uint32_t flat = 0xFFFFFFFFu - (uint32_t)(key & 0xFFFFFFFFull);
  if (flat >= (uint32_t)(H * W)) flat = 0;  // pad-key guard (shouldn't trigger)
  const int ix = (int)(flat % W);
  const int iy = (int)(flat / W);
  const float* img = scores + (size_t)b * H * W;

  float patch[25];
  float maxv = -INFINITY;
#pragma unroll
  for (int r = 0; r < 5; ++r) {
#pragma unroll
    for (int c = 0; c < 5; ++c) {
      int y = iy + r - 2, x = ix + c - 2;
      float v = (x >= 0 && x < W && y >= 0 && y < H) ? img[(size_t)y * W + x] : 0.0f;
      patch[r * 5 + c] = v;
      maxv = fmaxf(maxv, v);
    }
  }
  float e[25];
  float sum = 0.0f, sx = 0.0f, sy = 0.0f;
#pragma unroll
  for (int p = 0; p < 25; ++p) {
    float ev = expf((patch[p] - maxv) / 0.1f);
    e[p] = ev;
    sum += ev;
    sx += ev * (float)(p % 5 - 2);
    sy += ev * (float)(p / 5 - 2);
  }
  float rx = sx / sum, ry = sy / sum;
  float disp = 0.0f;
#pragma unroll
  for (int p = 0; p < 25; ++p) {
    float dx = ((float)(p % 5 - 2) - rx) * 0.5f;
    float dy = ((float)(p / 5 - 2) - ry) * 0.5f;
    disp += e[p] * (dx * dx + dy * dy);
  }
  disp /= sum;
  float kx = ((float)ix + rx) / 1023.0f * 2.0f - 1.0f;
  float ky = ((float)iy + ry) / 1023.0f * 2.0f - 1.0f;
  // bilinear sample with zero padding
  float px = (kx + 1.0f) * 0.5f * 1023.0f;
  float py = (ky + 1.0f) * 0.5f * 1023.0f;
  float x0f = floorf(px), y0f = floorf(py);
  float wx1 = px - x0f, wx0 = 1.0f - wx1;
  float wy1 = py - y0f, wy0 = 1.0f - wy1;
  int x0 = (int)x0f, y0 = (int)y0f;
  float sc = 0.0f;
  {
    int xs[2] = {x0, x0 + 1};
    int ys[2] = {y0, y0 + 1};
    float wxs[2] = {wx0, wx1};
    float wys[2] = {wy0, wy1};
#pragma unroll
    for (int yy = 0; yy < 2; ++yy)
#pragma unroll
      for (int xx = 0; xx < 2; ++xx) {
        int xi = xs[xx], yi = ys[yy];
        bool valid = (xi >= 0 && xi < W && yi >= 0 && yi < H);
        int xc = min(max(xi, 0), W - 1);
        int yc = min(max(yi, 0), H - 1);
        float v = valid ? img[(size_t)yc * W + xc] : 0.0f;
        sc += v * (wxs[xx] * wys[yy]);
      }
  }
  out[((size_t)b * TOPK + k) * 2 + 0] = kx;
  out[((size_t)b * TOPK + k) * 2 + 1] = ky;
  out[(size_t)B * TOPK * 2 + (size_t)b * TOPK + k] = sc;
  out[(size_t)B * TOPK * 3 + (size_t)b * TOPK + k] = disp;
}

}  // namespace

extern "C" void kernel_launch(void* const* d_in, const int* in_sizes, int n_in,
                              void* d_out, int out_size, void* d_ws, size_t ws_size,
                              hipStream_t stream) {
  const float* scores = (const float*)d_in[0];
  float* out = (float*)d_out;
  char* ws = (char*)d_ws;

  unsigned char* mask0 = (unsigned char*)(ws + OFF_MASK0);
  unsigned char* mask1 = (unsigned char*)(ws + OFF_MASK1);
  unsigned char* supp  = (unsigned char*)(ws + OFF_SUPP);
  uint32_t* hist = (uint32_t*)(ws + OFF_HIST);
  uint32_t* cnt  = (uint32_t*)(ws + OFF_CNT);
  uint32_t* cand_count = cnt;        // [B]
  uint32_t* sel_count  = cnt + 8;    // [B]
  uint32_t* thr        = cnt + 16;   // [B]
  uint64_t* sel  = (uint64_t*)(ws + OFF_SEL);
  uint64_t* topk = (uint64_t*)(ws + OFF_TOPK);
  uint64_t* cand = (uint64_t*)(ws + OFF_CAND);  // overlays mask0 (dead by then)

  // zero hist + counters (contiguous region)
  hipMemsetAsync(ws + OFF_HIST, 0, ((size_t)4 << 20) + 4096, stream);

  dim3 tb(TILE, TILE);
  dim3 tg(W / TILE, H / TILE, B);
  k_mask0<<<tg, tb, 0, stream>>>(scores, mask0);
  k_dilate<<<tg, tb, 0, stream>>>(mask0, supp);                       // supp1
  k_mask_update<<<tg, tb, 0, stream>>>(scores, supp, mask0, mask1);   // mask1
  k_dilate<<<tg, tb, 0, stream>>>(mask1, supp);                       // supp2
  k_emit<<<tg, tb, 0, stream>>>(scores, supp, mask1, cand, cand_count, hist);

  k_thresh<<<B, 1024, 0, stream>>>(hist, thr);
  k_compact<<<dim3(CAND_CAP / 256, B), 256, 0, stream>>>(cand, cand_count, thr, sel, sel_count);
  k_sort<<<B, 1024, 0, stream>>>(sel, sel_count, topk);
  k_refine<<<(B * TOPK + 255) / 256, 256, 0, stream>>>(scores, topk, out);
}

// Round 2
// 650.341 us; speedup vs baseline: 3.2378x; 3.2378x over previous
//
#include <hip/hip_runtime.h>
#include <stdint.h>

namespace {

constexpr int B = 8;
constexpr int H = 1024;
constexpr int W = 1024;
constexpr int TOPK = 4096;
constexpr int TILE = 32;
constexpr int HALO = 2;
constexpr int LT = TILE + 2 * HALO;  // 36
constexpr int CAND_CAP = 131072;     // per batch
constexpr int SEL_CAP = 8192;        // per batch (64 KB LDS sort)
constexpr int BLK_CAP = 384;         // max survivors per 32x32 tile (spacing>=3 => <=144; headroom for ties)

// workspace layout (bytes)
constexpr size_t OFF_MASK0 = 0;                               // B*H*W bytes = 8 MiB
constexpr size_t OFF_MASK1 = (size_t)8 << 20;                 // 8 MiB
constexpr size_t OFF_SUPP  = (size_t)16 << 20;                // 8 MiB
constexpr size_t OFF_CNT   = (size_t)24 << 20;                // counters+thr, 4 KiB
constexpr size_t OFF_SEL   = OFF_CNT + 4096;                  // B*SEL_CAP*8 = 512 KiB
constexpr size_t OFF_TOPK  = OFF_SEL + (size_t)B * SEL_CAP * 8; // B*TOPK*8 = 256 KiB
constexpr size_t OFF_CAND  = OFF_TOPK + (size_t)B * TOPK * 8; // B*CAND_CAP*8 = 8 MiB

__device__ __forceinline__ int ldsidx(int ly, int lx) { return ly * LT + lx; }

// P1: mask0 = (scores == maxpool5x5(scores))   [-inf padding]
__global__ void __launch_bounds__(1024) k_mask0(const float* __restrict__ scores,
                                                unsigned char* __restrict__ mask0) {
  __shared__ float sc[LT * LT];
  const int b = blockIdx.z;
  const int x0 = blockIdx.x * TILE - HALO;
  const int y0 = blockIdx.y * TILE - HALO;
  const float* img = scores + (size_t)b * H * W;
  const int tid = threadIdx.y * TILE + threadIdx.x;
  for (int i = tid; i < LT * LT; i += TILE * TILE) {
    int ly = i / LT, lx = i % LT;
    int gy = y0 + ly, gx = x0 + lx;
    float v = -INFINITY;
    if (gx >= 0 && gx < W && gy >= 0 && gy < H) v = img[gy * W + gx];
    sc[i] = v;
  }
  __syncthreads();
  const int lx = threadIdx.x + HALO, ly = threadIdx.y + HALO;
  float c = sc[ldsidx(ly, lx)];
  float m = -INFINITY;
#pragma unroll
  for (int dy = -2; dy <= 2; ++dy)
#pragma unroll
    for (int dx = -2; dx <= 2; ++dx) m = fmaxf(m, sc[ldsidx(ly + dy, lx + dx)]);
  int gy = y0 + ly, gx = x0 + lx;
  mask0[(size_t)b * H * W + gy * W + gx] = (c == m) ? 1 : 0;
}

// dilate: supp = any(mask in 5x5, in-bounds)
__global__ void __launch_bounds__(1024) k_dilate(const unsigned char* __restrict__ maskIn,
                                                 unsigned char* __restrict__ suppOut) {
  __shared__ unsigned char mk[LT * LT];
  const int b = blockIdx.z;
  const int x0 = blockIdx.x * TILE - HALO;
  const int y0 = blockIdx.y * TILE - HALO;
  const unsigned char* img = maskIn + (size_t)b * H * W;
  const int tid = threadIdx.y * TILE + threadIdx.x;
  for (int i = tid; i < LT * LT; i += TILE * TILE) {
    int ly = i / LT, lx = i % LT;
    int gy = y0 + ly, gx = x0 + lx;
    unsigned char v = 0;
    if (gx >= 0 && gx < W && gy >= 0 && gy < H) v = img[gy * W + gx];
    mk[i] = v;
  }
  __syncthreads();
  const int lx = threadIdx.x + HALO, ly = threadIdx.y + HALO;
  unsigned char any = 0;
#pragma unroll
  for (int dy = -2; dy <= 2; ++dy)
#pragma unroll
    for (int dx = -2; dx <= 2; ++dx) any |= mk[ldsidx(ly + dy, lx + dx)];
  int gy = y0 + ly, gx = x0 + lx;
  suppOut[(size_t)b * H * W + gy * W + gx] = any ? 1 : 0;
}

// refine pass: supp_scores = supp ? 0 : scores (outside image = -inf)
// new_max = (supp_scores == maxpool(supp_scores)); maskOut = maskIn | (new_max & !supp)
__global__ void __launch_bounds__(1024) k_mask_update(const float* __restrict__ scores,
                                                      const unsigned char* __restrict__ supp,
                                                      const unsigned char* __restrict__ maskIn,
                                                      unsigned char* __restrict__ maskOut) {
  __shared__ float ss[LT * LT];
  const int b = blockIdx.z;
  const int x0 = blockIdx.x * TILE - HALO;
  const int y0 = blockIdx.y * TILE - HALO;
  const size_t base = (size_t)b * H * W;
  const int tid = threadIdx.y * TILE + threadIdx.x;
  for (int i = tid; i < LT * LT; i += TILE * TILE) {
    int ly = i / LT, lx = i % LT;
    int gy = y0 + ly, gx = x0 + lx;
    float v = -INFINITY;
    if (gx >= 0 && gx < W && gy >= 0 && gy < H) {
      size_t g = base + (size_t)gy * W + gx;
      v = supp[g] ? 0.0f : scores[g];
    }
    ss[i] = v;
  }
  __syncthreads();
  const int lx = threadIdx.x + HALO, ly = threadIdx.y + HALO;
  float c = ss[ldsidx(ly, lx)];
  float m = -INFINITY;
#pragma unroll
  for (int dy = -2; dy <= 2; ++dy)
#pragma unroll
    for (int dx = -2; dx <= 2; ++dx) m = fmaxf(m, ss[ldsidx(ly + dy, lx + dx)]);
  int gy = y0 + ly, gx = x0 + lx;
  size_t g = base + (size_t)gy * W + gx;
  bool sp = supp[g] != 0;
  bool newmax = (c == m);
  maskOut[g] = (maskIn[g] || (newmax && !sp)) ? 1 : 0;
}

// final pass: mask2 = mask1 | (new_max2 & !supp2); emit candidates via per-block LDS compaction
__global__ void __launch_bounds__(1024) k_emit(const float* __restrict__ scores,
                                               const unsigned char* __restrict__ supp,
                                               const unsigned char* __restrict__ maskIn,
                                               uint64_t* __restrict__ cand,
                                               uint32_t* __restrict__ cand_count) {
  __shared__ float ss[LT * LT];
  __shared__ uint64_t list[BLK_CAP];
  __shared__ uint32_t cnt_loc;
  __shared__ uint32_t base_g;
  const int b = blockIdx.z;
  const int x0 = blockIdx.x * TILE - HALO;
  const int y0 = blockIdx.y * TILE - HALO;
  const size_t base = (size_t)b * H * W;
  const int tid = threadIdx.y * TILE + threadIdx.x;
  if (tid == 0) cnt_loc = 0;
  for (int i = tid; i < LT * LT; i += TILE * TILE) {
    int ly = i / LT, lx = i % LT;
    int gy = y0 + ly, gx = x0 + lx;
    float v = -INFINITY;
    if (gx >= 0 && gx < W && gy >= 0 && gy < H) {
      size_t g = base + (size_t)gy * W + gx;
      v = supp[g] ? 0.0f : scores[g];
    }
    ss[i] = v;
  }
  __syncthreads();
  const int lx = threadIdx.x + HALO, ly = threadIdx.y + HALO;
  float c = ss[ldsidx(ly, lx)];
  float m = -INFINITY;
#pragma unroll
  for (int dy = -2; dy <= 2; ++dy)
#pragma unroll
    for (int dx = -2; dx <= 2; ++dx) m = fmaxf(m, ss[ldsidx(ly + dy, lx + dx)]);
  int gy = y0 + ly, gx = x0 + lx;
  size_t g = base + (size_t)gy * W + gx;
  bool sp = supp[g] != 0;
  bool mask2 = maskIn[g] || ((c == m) && !sp);
  bool border = (gy < 2) || (gy >= H - 2) || (gx < 2) || (gx >= W - 2);
  uint64_t key = 0;
  uint32_t pos = 0xFFFFFFFFu;
  if (mask2 && !border) {
    float s = scores[g];  // original score (center may be suppressed in ss)
    if (s > 0.0f) {
      uint32_t bits = __float_as_uint(s);
      uint32_t flat = (uint32_t)(gy * W + gx);
      key = ((uint64_t)bits << 32) | (uint64_t)(0xFFFFFFFFu - flat);
      pos = atomicAdd(&cnt_loc, 1u);
      if (pos < (uint32_t)BLK_CAP) list[pos] = key;
    }
  }
  __syncthreads();
  uint32_t nblk = cnt_loc;
  uint32_t nmain = nblk < (uint32_t)BLK_CAP ? nblk : (uint32_t)BLK_CAP;
  if (tid == 0) base_g = atomicAdd(&cand_count[b], nmain);
  __syncthreads();
  uint32_t bg = base_g;
  for (uint32_t i = tid; i < nmain; i += 1024) {
    uint32_t p = bg + i;
    if (p < (uint32_t)CAND_CAP) cand[(size_t)b * CAND_CAP + p] = list[i];
  }
  // pathological overflow fallback (ties denser than BLK_CAP): direct global append
  if (pos != 0xFFFFFFFFu && pos >= (uint32_t)BLK_CAP) {
    uint32_t p = atomicAdd(&cand_count[b], 1u);
    if (p < (uint32_t)CAND_CAP) cand[(size_t)b * CAND_CAP + p] = key;
  }
}

// one block per batch: two-level radix threshold over candidates (LDS histograms only)
__global__ void __launch_bounds__(1024) k_select(const uint64_t* __restrict__ cand,
                                                 const uint32_t* __restrict__ cand_count,
                                                 uint64_t* __restrict__ thr_key) {
  __shared__ uint32_t h1[1024];
  __shared__ uint32_t h2[4096];
  __shared__ uint32_t shC;
  __shared__ uint32_t sh_above;
  const int b = blockIdx.x;
  const int t = threadIdx.x;
  uint32_t n = cand_count[b];
  if (n > (uint32_t)CAND_CAP) n = CAND_CAP;
  const uint64_t* cb = cand + (size_t)b * CAND_CAP;

  h1[t] = 0;
  if (t == 0) { shC = 0xFFFFFFFFu; sh_above = 0; }
  __syncthreads();
  for (uint32_t i = t; i < n; i += 1024) {
    uint32_t hi = (uint32_t)(cb[i] >> 54);  // top 10 bits of score float
    atomicAdd(&h1[hi], 1u);
  }
  __syncthreads();
  // suffix-sum h1 in place: h1[i] = sum_{k>=i}
  for (int d = 1; d < 1024; d <<= 1) {
    uint32_t v = (t + d < 1024) ? h1[t + d] : 0u;
    __syncthreads();
    h1[t] += v;
    __syncthreads();
  }
  if (h1[0] < (uint32_t)TOPK) {
    if (t == 0) thr_key[b] = 0ull;  // fewer than TOPK candidates: select all
    return;
  }
  {
    uint32_t mine = h1[t];
    uint32_t nxt = (t + 1 < 1024) ? h1[t + 1] : 0u;
    if (mine >= (uint32_t)TOPK && nxt < (uint32_t)TOPK) { shC = (uint32_t)t; sh_above = nxt; }
  }
  __syncthreads();
  const uint32_t C = shC;
  const uint32_t above = sh_above;

  // fine histogram on next 12 bits, only for candidates in coarse bucket C
#pragma unroll
  for (int j = 0; j < 4; ++j) h2[t + j * 1024] = 0;
  __syncthreads();
  for (uint32_t i = t; i < n; i += 1024) {
    uint64_t key = cb[i];
    if ((uint32_t)(key >> 54) == C) atomicAdd(&h2[(uint32_t)(key >> 42) & 0xFFFu], 1u);
  }
  __syncthreads();
  // suffix-sum h2 in place (4096 entries, 4 per thread, strided)
  for (int d = 1; d < 4096; d <<= 1) {
    uint32_t v[4];
#pragma unroll
    for (int j = 0; j < 4; ++j) {
      int i = t + j * 1024;
      v[j] = (i + d < 4096) ? h2[i + d] : 0u;
    }
    __syncthreads();
#pragma unroll
    for (int j = 0; j < 4; ++j) h2[t + j * 1024] += v[j];
    __syncthreads();
  }
#pragma unroll
  for (int j = 0; j < 4; ++j) {
    int f = t + j * 1024;
    uint32_t cum = above + h2[f];
    uint32_t cumn = (f + 1 < 4096) ? above + h2[f + 1] : above;
    if (cum >= (uint32_t)TOPK && cumn < (uint32_t)TOPK)
      thr_key[b] = ((uint64_t)C << 54) | ((uint64_t)f << 42);
  }
}

// compact candidates with key >= thr_key, per-block LDS aggregation
__global__ void __launch_bounds__(1024) k_compact(const uint64_t* __restrict__ cand,
                                                  const uint32_t* __restrict__ cand_count,
                                                  const uint64_t* __restrict__ thr_key,
                                                  uint64_t* __restrict__ sel,
                                                  uint32_t* __restrict__ sel_count) {
  __shared__ uint64_t list[1024];
  __shared__ uint32_t cnt_loc;
  __shared__ uint32_t base_g;
  const int b = blockIdx.y;
  uint32_t n = cand_count[b];
  if (n > (uint32_t)CAND_CAP) n = CAND_CAP;
  const int tid = threadIdx.x;
  if (tid == 0) cnt_loc = 0;
  __syncthreads();
  uint32_t i = blockIdx.x * 1024 + tid;
  if (i < n) {
    uint64_t key = cand[(size_t)b * CAND_CAP + i];
    if (key >= thr_key[b]) {
      uint32_t pos = atomicAdd(&cnt_loc, 1u);
      list[pos] = key;
    }
  }
  __syncthreads();
  uint32_t nblk = cnt_loc;
  if (tid == 0 && nblk > 0) base_g = atomicAdd(&sel_count[b], nblk);
  __syncthreads();
  if (nblk > 0) {
    uint32_t bg = base_g;
    if (tid < nblk) {
      uint32_t p = bg + tid;
      if (p < (uint32_t)SEL_CAP) sel[(size_t)b * SEL_CAP + p] = list[tid];
    }
  }
}

// one block per batch: bitonic sort SEL_CAP keys descending, write top TOPK
__global__ void __launch_bounds__(1024) k_sort(const uint64_t* __restrict__ sel,
                                               const uint32_t* __restrict__ sel_count,
                                               uint64_t* __restrict__ topk) {
  __shared__ uint64_t keys[SEL_CAP];  // 64 KiB
  const int b = blockIdx.x;
  uint32_t n = sel_count[b];
  if (n > (uint32_t)SEL_CAP) n = SEL_CAP;
  for (int i = threadIdx.x; i < SEL_CAP; i += 1024)
    keys[i] = ((uint32_t)i < n) ? sel[(size_t)b * SEL_CAP + i] : 0ull;
  __syncthreads();
  for (unsigned k = 2; k <= (unsigned)SEL_CAP; k <<= 1) {
    for (unsigned j = k >> 1; j > 0; j >>= 1) {
      for (unsigned t = threadIdx.x; t < (unsigned)SEL_CAP; t += 1024) {
        unsigned p = t ^ j;
        if (p > t) {
          uint64_t a = keys[t], c = keys[p];
          bool desc = ((t & k) == 0);
          if ((a < c) == desc) { keys[t] = c; keys[p] = a; }
        }
      }
      __syncthreads();
    }
  }
  for (int i = threadIdx.x; i < TOPK; i += 1024)
    topk[(size_t)b * TOPK + i] = keys[i];
}

// per-keypoint refinement: softargmax residual, dispersity, bilinear score
__global__ void k_refine(const float* __restrict__ scores,
                         const uint64_t* __restrict__ topk,
                         float* __restrict__ out) {
  int gid = blockIdx.x * blockDim.x + threadIdx.x;
  if (gid >= B * TOPK) return;
  const int b = gid / TOPK;
  const int k = gid % TOPK;
  uint64_t key = topk[(size_t)b * TOPK + k];
  uint32_t flat = 0xFFFFFFFFu - (uint32_t)(key & 0xFFFFFFFFull);
  if (flat >= (uint32_t)(H * W)) flat = 0;  // pad-key guard
  const int ix = (int)(flat % W);
  const int iy = (int)(flat / W);
  const float* img = scores + (size_t)b * H * W;

  float patch[25];
  float maxv = -INFINITY;
#pragma unroll
  for (int r = 0; r < 5; ++r) {
#pragma unroll
    for (int c = 0; c < 5; ++c) {
      int y = iy + r - 2, x = ix + c - 2;
      float v = (x >= 0 && x < W && y >= 0 && y < H) ? img[(size_t)y * W + x] : 0.0f;
      patch[r * 5 + c] = v;
      maxv = fmaxf(maxv, v);
    }
  }
  float e[25];
  float sum = 0.0f, sx = 0.0f, sy = 0.0f;
#pragma unroll
  for (int p = 0; p < 25; ++p) {
    float ev = expf((patch[p] - maxv) / 0.1f);
    e[p] = ev;
    sum += ev;
    sx += ev * (float)(p % 5 - 2);
    sy += ev * (float)(p / 5 - 2);
  }
  float rx = sx / sum, ry = sy / sum;
  float disp = 0.0f;
#pragma unroll
  for (int p = 0; p < 25; ++p) {
    float dx = ((float)(p % 5 - 2) - rx) * 0.5f;
    float dy = ((float)(p / 5 - 2) - ry) * 0.5f;
    disp += e[p] * (dx * dx + dy * dy);
  }
  disp /= sum;
  float kx = ((float)ix + rx) / 1023.0f * 2.0f - 1.0f;
  float ky = ((float)iy + ry) / 1023.0f * 2.0f - 1.0f;
  float px = (kx + 1.0f) * 0.5f * 1023.0f;
  float py = (ky + 1.0f) * 0.5f * 1023.0f;
  float x0f = floorf(px), y0f = floorf(py);
  float wx1 = px - x0f, wx0 = 1.0f - wx1;
  float wy1 = py - y0f, wy0 = 1.0f - wy1;
  int x0 = (int)x0f, y0 = (int)y0f;
  float sc = 0.0f;
  {
    int xs[2] = {x0, x0 + 1};
    int ys[2] = {y0, y0 + 1};
    float wxs[2] = {wx0, wx1};
    float wys[2] = {wy0, wy1};
#pragma unroll
    for (int yy = 0; yy < 2; ++yy)
#pragma unroll
      for (int xx = 0; xx < 2; ++xx) {
        int xi = xs[xx], yi = ys[yy];
        bool valid = (xi >= 0 && xi < W && yi >= 0 && yi < H);
        int xc = min(max(xi, 0), W - 1);
        int yc = min(max(yi, 0), H - 1);
        float v = valid ? img[(size_t)yc * W + xc] : 0.0f;
        sc += v * (wxs[xx] * wys[yy]);
      }
  }
  out[((size_t)b * TOPK + k) * 2 + 0] = kx;
  out[((size_t)b * TOPK + k) * 2 + 1] = ky;
  out[(size_t)B * TOPK * 2 + (size_t)b * TOPK + k] = sc;
  out[(size_t)B * TOPK * 3 + (size_t)b * TOPK + k] = disp;
}

}  // namespace

extern "C" void kernel_launch(void* const* d_in, const int* in_sizes, int n_in,
                              void* d_out, int out_size, void* d_ws, size_t ws_size,
                              hipStream_t stream) {
  const float* scores = (const float*)d_in[0];
  float* out = (float*)d_out;
  char* ws = (char*)d_ws;

  unsigned char* mask0 = (unsigned char*)(ws + OFF_MASK0);
  unsigned char* mask1 = (unsigned char*)(ws + OFF_MASK1);
  unsigned char* supp  = (unsigned char*)(ws + OFF_SUPP);
  uint32_t* cnt  = (uint32_t*)(ws + OFF_CNT);
  uint32_t* cand_count = cnt;                       // [B]
  uint32_t* sel_count  = cnt + 8;                   // [B]
  uint64_t* thr_key    = (uint64_t*)(cnt + 16);     // [B], 8-byte aligned
  uint64_t* sel  = (uint64_t*)(ws + OFF_SEL);
  uint64_t* topk = (uint64_t*)(ws + OFF_TOPK);
  uint64_t* cand = (uint64_t*)(ws + OFF_CAND);

  // zero counters only
  hipMemsetAsync(ws + OFF_CNT, 0, 4096, stream);

  dim3 tb(TILE, TILE);
  dim3 tg(W / TILE, H / TILE, B);
  k_mask0<<<tg, tb, 0, stream>>>(scores, mask0);
  k_dilate<<<tg, tb, 0, stream>>>(mask0, supp);                       // supp1
  k_mask_update<<<tg, tb, 0, stream>>>(scores, supp, mask0, mask1);   // mask1
  k_dilate<<<tg, tb, 0, stream>>>(mask1, supp);                       // supp2
  k_emit<<<tg, tb, 0, stream>>>(scores, supp, mask1, cand, cand_count);

  k_select<<<B, 1024, 0, stream>>>(cand, cand_count, thr_key);
  k_compact<<<dim3(CAND_CAP / 1024, B), 1024, 0, stream>>>(cand, cand_count, thr_key, sel, sel_count);
  k_sort<<<B, 1024, 0, stream>>>(sel, sel_count, topk);
  k_refine<<<(B * TOPK + 255) / 256, 256, 0, stream>>>(scores, topk, out);
}

// Round 3
// 403.353 us; speedup vs baseline: 5.2204x; 1.6123x over previous
//
#include <hip/hip_runtime.h>
#include <stdint.h>

namespace {

constexpr int B = 8;
constexpr int H = 1024;
constexpr int W = 1024;
constexpr int WW = W / 4;            // mask words per row
constexpr int TOPK = 4096;
constexpr int TSX = 64;              // tile width (px)
constexpr int TSY = 16;              // tile height (px)
constexpr int NTH = 256;             // 16 x 16 threads
constexpr int SC_H = 20;             // staged rows (TSY + 2*2)
constexpr int SC_STRIDE = 76;        // 72 staged floats + pad
constexpr int HB_STRIDE = 68;        // 64 + pad
constexpr int MW = 18;               // staged mask words per row (16 + 1 each side)
constexpr int MW_STRIDE = 19;
constexpr int CAND_CAP = 131072;     // per batch
constexpr int SEL_CAP = 8192;        // per batch
constexpr int BLK_CAP = 256;         // survivors per 64x16 tile (spacing>=3 => ~138 max + ties)

// workspace layout (bytes)
constexpr size_t OFF_MASK0 = 0;                                  // 8 MiB (u32 words)
constexpr size_t OFF_MASK1 = (size_t)8 << 20;                    // 8 MiB
constexpr size_t OFF_SUPP  = (size_t)16 << 20;                   // 8 MiB
constexpr size_t OFF_CNT   = (size_t)24 << 20;                   // 4 KiB counters
constexpr size_t OFF_SEL   = OFF_CNT + 4096;                     // 512 KiB
constexpr size_t OFF_TOPK  = OFF_SEL + (size_t)B * SEL_CAP * 8;  // 256 KiB
constexpr size_t OFF_CAND  = OFF_TOPK + (size_t)B * TOPK * 8;    // 8 MiB

__device__ __forceinline__ float max5(float a, float b, float c, float d, float e) {
  return fmaxf(fmaxf(fmaxf(a, b), fmaxf(c, d)), e);
}

// ---------------- stencil pass 1: mask0 = (sc == max5x5(sc)), bitpacked u8-in-u32 ----
__global__ void __launch_bounds__(NTH) k_mask0(const float* __restrict__ scores,
                                               uint32_t* __restrict__ mask0) {
  __shared__ float sc[SC_H][SC_STRIDE];
  __shared__ float hb[SC_H][HB_STRIDE];
  const int b = blockIdx.z;
  const int x0 = blockIdx.x * TSX, y0 = blockIdx.y * TSY;
  const int tx = threadIdx.x, ty = threadIdx.y;
  const int tid = ty * 16 + tx;
  const float* img = scores + (size_t)b * H * W;
  for (int i = tid; i < SC_H * 18; i += NTH) {
    int r = i / 18, c = i % 18;
    int gy = y0 - 2 + r;
    int gx = x0 - 4 + 4 * c;  // multiple of 4; fully in or fully out
    float4 v;
    if (gy >= 0 && gy < H && gx >= 0 && gx < W)
      v = *reinterpret_cast<const float4*>(img + (size_t)gy * W + gx);
    else
      v = make_float4(-INFINITY, -INFINITY, -INFINITY, -INFINITY);
    *reinterpret_cast<float4*>(&sc[r][4 * c]) = v;
  }
  __syncthreads();
  for (int r = ty; r < SC_H; r += 16) {
    float4 a = *reinterpret_cast<const float4*>(&sc[r][4 * tx]);
    float4 d = *reinterpret_cast<const float4*>(&sc[r][4 * tx + 4]);
    float4 e = *reinterpret_cast<const float4*>(&sc[r][4 * tx + 8]);
    float4 hm;
    hm.x = max5(a.z, a.w, d.x, d.y, d.z);
    hm.y = max5(a.w, d.x, d.y, d.z, d.w);
    hm.z = max5(d.x, d.y, d.z, d.w, e.x);
    hm.w = max5(d.y, d.z, d.w, e.x, e.y);
    *reinterpret_cast<float4*>(&hb[r][4 * tx]) = hm;
  }
  __syncthreads();
  float4 m0 = *reinterpret_cast<const float4*>(&hb[ty + 0][4 * tx]);
  float4 m1 = *reinterpret_cast<const float4*>(&hb[ty + 1][4 * tx]);
  float4 m2 = *reinterpret_cast<const float4*>(&hb[ty + 2][4 * tx]);
  float4 m3 = *reinterpret_cast<const float4*>(&hb[ty + 3][4 * tx]);
  float4 m4 = *reinterpret_cast<const float4*>(&hb[ty + 4][4 * tx]);
  float4 vm;
  vm.x = max5(m0.x, m1.x, m2.x, m3.x, m4.x);
  vm.y = max5(m0.y, m1.y, m2.y, m3.y, m4.y);
  vm.z = max5(m0.z, m1.z, m2.z, m3.z, m4.z);
  vm.w = max5(m0.w, m1.w, m2.w, m3.w, m4.w);
  float4 c = *reinterpret_cast<const float4*>(&sc[ty + 2][4 * tx + 4]);
  uint32_t wrd = (uint32_t)(c.x == vm.x) | ((uint32_t)(c.y == vm.y) << 8) |
                 ((uint32_t)(c.z == vm.z) << 16) | ((uint32_t)(c.w == vm.w) << 24);
  mask0[((size_t)b * H + (y0 + ty)) * WW + x0 / 4 + tx] = wrd;
}

// ---------------- dilate on bitpacked masks: supp = any(mask in 5x5) -----------------
__global__ void __launch_bounds__(NTH) k_dilate(const uint32_t* __restrict__ mIn,
                                                uint32_t* __restrict__ mOut) {
  __shared__ uint32_t mk[SC_H][MW_STRIDE];
  __shared__ uint32_t hd[SC_H][17];
  const int b = blockIdx.z;
  const int x0 = blockIdx.x * TSX, y0 = blockIdx.y * TSY;
  const int tx = threadIdx.x, ty = threadIdx.y;
  const int tid = ty * 16 + tx;
  for (int i = tid; i < SC_H * MW; i += NTH) {
    int r = i / MW, cc = i % MW;
    int gy = y0 - 2 + r;
    int wx = x0 / 4 - 1 + cc;
    uint32_t v = 0;
    if (gy >= 0 && gy < H && wx >= 0 && wx < WW) v = mIn[((size_t)b * H + gy) * WW + wx];
    mk[r][cc] = v;
  }
  __syncthreads();
  for (int r = ty; r < SC_H; r += 16) {
    uint32_t w0 = mk[r][tx], w1 = mk[r][tx + 1], w2 = mk[r][tx + 2];
    unsigned long long a = (unsigned long long)w0 | ((unsigned long long)w1 << 32);
    unsigned long long c = (unsigned long long)w1 | ((unsigned long long)w2 << 32);
    unsigned long long A = a | (a >> 8) | (a >> 16) | (a >> 24) | (a >> 32);
    unsigned long long C = c | (c >> 8) | (c >> 16) | (c >> 24) | (c >> 32);
    hd[r][tx] = (uint32_t)(((A >> 16) & 0xFFFFull) | ((C & 0xFFFFull) << 16));
  }
  __syncthreads();
  uint32_t o = hd[ty][tx] | hd[ty + 1][tx] | hd[ty + 2][tx] | hd[ty + 3][tx] | hd[ty + 4][tx];
  mOut[((size_t)b * H + (y0 + ty)) * WW + x0 / 4 + tx] = o;
}

// ---------------- mask refine: maskOut = maskIn | (newmax(ss) & ~supp) ---------------
__global__ void __launch_bounds__(NTH) k_mask_update(const float* __restrict__ scores,
                                                     const uint32_t* __restrict__ supp,
                                                     const uint32_t* __restrict__ maskIn,
                                                     uint32_t* __restrict__ maskOut) {
  __shared__ float ssv[SC_H][SC_STRIDE];
  __shared__ float hb[SC_H][HB_STRIDE];
  __shared__ uint32_t sw[SC_H][MW_STRIDE];
  const int b = blockIdx.z;
  const int x0 = blockIdx.x * TSX, y0 = blockIdx.y * TSY;
  const int tx = threadIdx.x, ty = threadIdx.y;
  const int tid = ty * 16 + tx;
  const float* img = scores + (size_t)b * H * W;
  for (int i = tid; i < SC_H * 18; i += NTH) {
    int r = i / 18, c = i % 18;
    int gy = y0 - 2 + r;
    int gx = x0 - 4 + 4 * c;
    int wx = x0 / 4 - 1 + c;
    uint32_t s = 0;
    float4 v = make_float4(-INFINITY, -INFINITY, -INFINITY, -INFINITY);
    if (gy >= 0 && gy < H && gx >= 0 && gx < W) {
      s = supp[((size_t)b * H + gy) * WW + wx];
      v = *reinterpret_cast<const float4*>(img + (size_t)gy * W + gx);
      if (s & 0xFFu) v.x = 0.0f;
      if (s & 0xFF00u) v.y = 0.0f;
      if (s & 0xFF0000u) v.z = 0.0f;
      if (s & 0xFF000000u) v.w = 0.0f;
    }
    sw[r][c] = s;
    *reinterpret_cast<float4*>(&ssv[r][4 * c]) = v;
  }
  __syncthreads();
  for (int r = ty; r < SC_H; r += 16) {
    float4 a = *reinterpret_cast<const float4*>(&ssv[r][4 * tx]);
    float4 d = *reinterpret_cast<const float4*>(&ssv[r][4 * tx + 4]);
    float4 e = *reinterpret_cast<const float4*>(&ssv[r][4 * tx + 8]);
    float4 hm;
    hm.x = max5(a.z, a.w, d.x, d.y, d.z);
    hm.y = max5(a.w, d.x, d.y, d.z, d.w);
    hm.z = max5(d.x, d.y, d.z, d.w, e.x);
    hm.w = max5(d.y, d.z, d.w, e.x, e.y);
    *reinterpret_cast<float4*>(&hb[r][4 * tx]) = hm;
  }
  __syncthreads();
  float4 m0 = *reinterpret_cast<const float4*>(&hb[ty + 0][4 * tx]);
  float4 m1 = *reinterpret_cast<const float4*>(&hb[ty + 1][4 * tx]);
  float4 m2 = *reinterpret_cast<const float4*>(&hb[ty + 2][4 * tx]);
  float4 m3 = *reinterpret_cast<const float4*>(&hb[ty + 3][4 * tx]);
  float4 m4 = *reinterpret_cast<const float4*>(&hb[ty + 4][4 * tx]);
  float4 vm;
  vm.x = max5(m0.x, m1.x, m2.x, m3.x, m4.x);
  vm.y = max5(m0.y, m1.y, m2.y, m3.y, m4.y);
  vm.z = max5(m0.z, m1.z, m2.z, m3.z, m4.z);
  vm.w = max5(m0.w, m1.w, m2.w, m3.w, m4.w);
  float4 c = *reinterpret_cast<const float4*>(&ssv[ty + 2][4 * tx + 4]);
  uint32_t nm = (uint32_t)(c.x == vm.x) | ((uint32_t)(c.y == vm.y) << 8) |
                ((uint32_t)(c.z == vm.z) << 16) | ((uint32_t)(c.w == vm.w) << 24);
  uint32_t sWrd = sw[ty + 2][tx + 1];
  size_t gw = ((size_t)b * H + (y0 + ty)) * WW + x0 / 4 + tx;
  maskOut[gw] = maskIn[gw] | (nm & ~sWrd);
}

// ---------------- final pass: mask2 & border -> emit candidate keys ------------------
__global__ void __launch_bounds__(NTH) k_emit(const float* __restrict__ scores,
                                              const uint32_t* __restrict__ supp,
                                              const uint32_t* __restrict__ maskIn,
                                              uint64_t* __restrict__ cand,
                                              uint32_t* __restrict__ cand_count) {
  __shared__ float ssv[SC_H][SC_STRIDE];
  __shared__ float hb[SC_H][HB_STRIDE];
  __shared__ uint32_t sw[SC_H][MW_STRIDE];
  __shared__ uint64_t list[BLK_CAP];
  __shared__ uint32_t cnt_loc;
  __shared__ uint32_t base_g;
  const int b = blockIdx.z;
  const int x0 = blockIdx.x * TSX, y0 = blockIdx.y * TSY;
  const int tx = threadIdx.x, ty = threadIdx.y;
  const int tid = ty * 16 + tx;
  const float* img = scores + (size_t)b * H * W;
  if (tid == 0) cnt_loc = 0;
  for (int i = tid; i < SC_H * 18; i += NTH) {
    int r = i / 18, c = i % 18;
    int gy = y0 - 2 + r;
    int gx = x0 - 4 + 4 * c;
    int wx = x0 / 4 - 1 + c;
    uint32_t s = 0;
    float4 v = make_float4(-INFINITY, -INFINITY, -INFINITY, -INFINITY);
    if (gy >= 0 && gy < H && gx >= 0 && gx < W) {
      s = supp[((size_t)b * H + gy) * WW + wx];
      v = *reinterpret_cast<const float4*>(img + (size_t)gy * W + gx);
      if (s & 0xFFu) v.x = 0.0f;
      if (s & 0xFF00u) v.y = 0.0f;
      if (s & 0xFF0000u) v.z = 0.0f;
      if (s & 0xFF000000u) v.w = 0.0f;
    }
    sw[r][c] = s;
    *reinterpret_cast<float4*>(&ssv[r][4 * c]) = v;
  }
  __syncthreads();
  for (int r = ty; r < SC_H; r += 16) {
    float4 a = *reinterpret_cast<const float4*>(&ssv[r][4 * tx]);
    float4 d = *reinterpret_cast<const float4*>(&ssv[r][4 * tx + 4]);
    float4 e = *reinterpret_cast<const float4*>(&ssv[r][4 * tx + 8]);
    float4 hm;
    hm.x = max5(a.z, a.w, d.x, d.y, d.z);
    hm.y = max5(a.w, d.x, d.y, d.z, d.w);
    hm.z = max5(d.x, d.y, d.z, d.w, e.x);
    hm.w = max5(d.y, d.z, d.w, e.x, e.y);
    *reinterpret_cast<float4*>(&hb[r][4 * tx]) = hm;
  }
  __syncthreads();
  float4 m0 = *reinterpret_cast<const float4*>(&hb[ty + 0][4 * tx]);
  float4 m1 = *reinterpret_cast<const float4*>(&hb[ty + 1][4 * tx]);
  float4 m2 = *reinterpret_cast<const float4*>(&hb[ty + 2][4 * tx]);
  float4 m3 = *reinterpret_cast<const float4*>(&hb[ty + 3][4 * tx]);
  float4 m4 = *reinterpret_cast<const float4*>(&hb[ty + 4][4 * tx]);
  float4 vm;
  vm.x = max5(m0.x, m1.x, m2.x, m3.x, m4.x);
  vm.y = max5(m0.y, m1.y, m2.y, m3.y, m4.y);
  vm.z = max5(m0.z, m1.z, m2.z, m3.z, m4.z);
  vm.w = max5(m0.w, m1.w, m2.w, m3.w, m4.w);
  float4 c = *reinterpret_cast<const float4*>(&ssv[ty + 2][4 * tx + 4]);
  uint32_t nm = (uint32_t)(c.x == vm.x) | ((uint32_t)(c.y == vm.y) << 8) |
                ((uint32_t)(c.z == vm.z) << 16) | ((uint32_t)(c.w == vm.w) << 24);
  uint32_t sWrd = sw[ty + 2][tx + 1];
  size_t gw = ((size_t)b * H + (y0 + ty)) * WW + x0 / 4 + tx;
  uint32_t m2w = maskIn[gw] | (nm & ~sWrd);
  const int gy = y0 + ty;
  if (gy < 2 || gy > H - 3) m2w = 0;
  uint64_t mykeys[4];
  int nmine = 0;
  if (m2w) {
#pragma unroll
    for (int j = 0; j < 4; ++j) {
      if ((m2w >> (8 * j)) & 1u) {
        int gx = x0 + 4 * tx + j;
        if (gx >= 2 && gx <= W - 3) {
          float s = img[(size_t)gy * W + gx];  // original score
          if (s > 0.0f) {
            uint32_t bits = __float_as_uint(s);
            uint32_t flat = (uint32_t)(gy * W + gx);
            mykeys[nmine++] = ((uint64_t)bits << 32) | (uint64_t)(0xFFFFFFFFu - flat);
          }
        }
      }
    }
  }
  uint32_t pos = 0xFFFFFFFFu;
  if (nmine > 0) pos = atomicAdd(&cnt_loc, (uint32_t)nmine);
  for (int j = 0; j < nmine; ++j)
    if (pos + j < (uint32_t)BLK_CAP) list[pos + j] = mykeys[j];
  __syncthreads();
  uint32_t nblk = cnt_loc;
  uint32_t nmain = nblk < (uint32_t)BLK_CAP ? nblk : (uint32_t)BLK_CAP;
  if (tid == 0) base_g = atomicAdd(&cand_count[b], nmain);
  __syncthreads();
  uint32_t bg = base_g;
  for (uint32_t i = tid; i < nmain; i += NTH) {
    uint32_t p = bg + i;
    if (p < (uint32_t)CAND_CAP) cand[(size_t)b * CAND_CAP + p] = list[i];
  }
  // overflow fallback (ties denser than BLK_CAP): direct global append
  for (int j = 0; j < nmine; ++j) {
    if (pos + j >= (uint32_t)BLK_CAP) {
      uint32_t p = atomicAdd(&cand_count[b], 1u);
      if (p < (uint32_t)CAND_CAP) cand[(size_t)b * CAND_CAP + p] = mykeys[j];
    }
  }
}

// ---------------- two-level radix threshold (unchanged) ------------------------------
__global__ void __launch_bounds__(1024) k_select(const uint64_t* __restrict__ cand,
                                                 const uint32_t* __restrict__ cand_count,
                                                 uint64_t* __restrict__ thr_key) {
  __shared__ uint32_t h1[1024];
  __shared__ uint32_t h2[4096];
  __shared__ uint32_t shC;
  __shared__ uint32_t sh_above;
  const int b = blockIdx.x;
  const int t = threadIdx.x;
  uint32_t n = cand_count[b];
  if (n > (uint32_t)CAND_CAP) n = CAND_CAP;
  const uint64_t* cb = cand + (size_t)b * CAND_CAP;

  h1[t] = 0;
  if (t == 0) { shC = 0xFFFFFFFFu; sh_above = 0; }
  __syncthreads();
  for (uint32_t i = t; i < n; i += 1024) atomicAdd(&h1[(uint32_t)(cb[i] >> 54)], 1u);
  __syncthreads();
  for (int d = 1; d < 1024; d <<= 1) {
    uint32_t v = (t + d < 1024) ? h1[t + d] : 0u;
    __syncthreads();
    h1[t] += v;
    __syncthreads();
  }
  if (h1[0] < (uint32_t)TOPK) {
    if (t == 0) thr_key[b] = 0ull;
    return;
  }
  {
    uint32_t mine = h1[t];
    uint32_t nxt = (t + 1 < 1024) ? h1[t + 1] : 0u;
    if (mine >= (uint32_t)TOPK && nxt < (uint32_t)TOPK) { shC = (uint32_t)t; sh_above = nxt; }
  }
  __syncthreads();
  const uint32_t C = shC;
  const uint32_t above = sh_above;
#pragma unroll
  for (int j = 0; j < 4; ++j) h2[t + j * 1024] = 0;
  __syncthreads();
  for (uint32_t i = t; i < n; i += 1024) {
    uint64_t key = cb[i];
    if ((uint32_t)(key >> 54) == C) atomicAdd(&h2[(uint32_t)(key >> 42) & 0xFFFu], 1u);
  }
  __syncthreads();
  for (int d = 1; d < 4096; d <<= 1) {
    uint32_t v[4];
#pragma unroll
    for (int j = 0; j < 4; ++j) {
      int i = t + j * 1024;
      v[j] = (i + d < 4096) ? h2[i + d] : 0u;
    }
    __syncthreads();
#pragma unroll
    for (int j = 0; j < 4; ++j) h2[t + j * 1024] += v[j];
    __syncthreads();
  }
#pragma unroll
  for (int j = 0; j < 4; ++j) {
    int f = t + j * 1024;
    uint32_t cum = above + h2[f];
    uint32_t cumn = (f + 1 < 4096) ? above + h2[f + 1] : above;
    if (cum >= (uint32_t)TOPK && cumn < (uint32_t)TOPK)
      thr_key[b] = ((uint64_t)C << 54) | ((uint64_t)f << 42);
  }
}

// ---------------- compact (unchanged) ------------------------------------------------
__global__ void __launch_bounds__(1024) k_compact(const uint64_t* __restrict__ cand,
                                                  const uint32_t* __restrict__ cand_count,
                                                  const uint64_t* __restrict__ thr_key,
                                                  uint64_t* __restrict__ sel,
                                                  uint32_t* __restrict__ sel_count) {
  __shared__ uint64_t list[1024];
  __shared__ uint32_t cnt_loc;
  __shared__ uint32_t base_g;
  const int b = blockIdx.y;
  uint32_t n = cand_count[b];
  if (n > (uint32_t)CAND_CAP) n = CAND_CAP;
  const int tid = threadIdx.x;
  if (tid == 0) cnt_loc = 0;
  __syncthreads();
  uint32_t i = blockIdx.x * 1024 + tid;
  if (i < n) {
    uint64_t key = cand[(size_t)b * CAND_CAP + i];
    if (key >= thr_key[b]) {
      uint32_t pos = atomicAdd(&cnt_loc, 1u);
      list[pos] = key;
    }
  }
  __syncthreads();
  uint32_t nblk = cnt_loc;
  if (tid == 0 && nblk > 0) base_g = atomicAdd(&sel_count[b], nblk);
  __syncthreads();
  if (nblk > 0 && (uint32_t)tid < nblk) {
    uint32_t p = base_g + tid;
    if (p < (uint32_t)SEL_CAP) sel[(size_t)b * SEL_CAP + p] = list[tid];
  }
}

// ---------------- exact ranking replaces bitonic sort --------------------------------
// keys are distinct (flat idx in low bits) => rank = #{keys > mine} is a permutation;
// topk[rank] = key reproduces JAX top_k order exactly (desc value, asc index on ties).
__global__ void __launch_bounds__(1024) k_rank(const uint64_t* __restrict__ sel,
                                               const uint32_t* __restrict__ sel_count,
                                               uint64_t* __restrict__ topk) {
  __shared__ uint64_t keys[SEL_CAP];  // 64 KiB
  const int b = blockIdx.y;
  uint32_t n = sel_count[b];
  if (n > (uint32_t)SEL_CAP) n = SEL_CAP;
  uint32_t i0 = blockIdx.x * 1024;
  if (i0 >= n) return;
  const uint64_t* sb = sel + (size_t)b * SEL_CAP;
  for (uint32_t i = threadIdx.x; i < n; i += 1024) keys[i] = sb[i];
  __syncthreads();
  uint32_t me = i0 + threadIdx.x;
  if (me >= n) return;
  uint64_t kme = keys[me];
  uint32_t rank = 0;
  uint32_t i = 0;
  for (; i + 8 <= n; i += 8) {  // uniform loop: LDS broadcast reads, conflict-free
    rank += (keys[i] > kme);
    rank += (keys[i + 1] > kme);
    rank += (keys[i + 2] > kme);
    rank += (keys[i + 3] > kme);
    rank += (keys[i + 4] > kme);
    rank += (keys[i + 5] > kme);
    rank += (keys[i + 6] > kme);
    rank += (keys[i + 7] > kme);
  }
  for (; i < n; ++i) rank += (keys[i] > kme);
  if (rank < (uint32_t)TOPK) topk[(size_t)b * TOPK + rank] = kme;
}

// ---------------- per-keypoint refinement (unchanged) --------------------------------
__global__ void k_refine(const float* __restrict__ scores,
                         const uint64_t* __restrict__ topk,
                         float* __restrict__ out) {
  int gid = blockIdx.x * blockDim.x + threadIdx.x;
  if (gid >= B * TOPK) return;
  const int b = gid / TOPK;
  const int k = gid % TOPK;
  uint64_t key = topk[(size_t)b * TOPK + k];
  uint32_t flat = 0xFFFFFFFFu - (uint32_t)(key & 0xFFFFFFFFull);
  if (flat >= (uint32_t)(H * W)) flat = 0;  // pad-key guard
  const int ix = (int)(flat % W);
  const int iy = (int)(flat / W);
  const float* img = scores + (size_t)b * H * W;

  float patch[25];
  float maxv = -INFINITY;
#pragma unroll
  for (int r = 0; r < 5; ++r) {
#pragma unroll
    for (int c = 0; c < 5; ++c) {
      int y = iy + r - 2, x = ix + c - 2;
      float v = (x >= 0 && x < W && y >= 0 && y < H) ? img[(size_t)y * W + x] : 0.0f;
      patch[r * 5 + c] = v;
      maxv = fmaxf(maxv, v);
    }
  }
  float e[25];
  float sum = 0.0f, sx = 0.0f, sy = 0.0f;
#pragma unroll
  for (int p = 0; p < 25; ++p) {
    float ev = expf((patch[p] - maxv) / 0.1f);
    e[p] = ev;
    sum += ev;
    sx += ev * (float)(p % 5 - 2);
    sy += ev * (float)(p / 5 - 2);
  }
  float rx = sx / sum, ry = sy / sum;
  float disp = 0.0f;
#pragma unroll
  for (int p = 0; p < 25; ++p) {
    float dx = ((float)(p % 5 - 2) - rx) * 0.5f;
    float dy = ((float)(p / 5 - 2) - ry) * 0.5f;
    disp += e[p] * (dx * dx + dy * dy);
  }
  disp /= sum;
  float kx = ((float)ix + rx) / 1023.0f * 2.0f - 1.0f;
  float ky = ((float)iy + ry) / 1023.0f * 2.0f - 1.0f;
  float px = (kx + 1.0f) * 0.5f * 1023.0f;
  float py = (ky + 1.0f) * 0.5f * 1023.0f;
  float x0f = floorf(px), y0f = floorf(py);
  float wx1 = px - x0f, wx0 = 1.0f - wx1;
  float wy1 = py - y0f, wy0 = 1.0f - wy1;
  int x0 = (int)x0f, y0 = (int)y0f;
  float sc = 0.0f;
  {
    int xs[2] = {x0, x0 + 1};
    int ys[2] = {y0, y0 + 1};
    float wxs[2] = {wx0, wx1};
    float wys[2] = {wy0, wy1};
#pragma unroll
    for (int yy = 0; yy < 2; ++yy)
#pragma unroll
      for (int xx = 0; xx < 2; ++xx) {
        int xi = xs[xx], yi = ys[yy];
        bool valid = (xi >= 0 && xi < W && yi >= 0 && yi < H);
        int xc = min(max(xi, 0), W - 1);
        int yc = min(max(yi, 0), H - 1);
        float v = valid ? img[(size_t)yc * W + xc] : 0.0f;
        sc += v * (wxs[xx] * wys[yy]);
      }
  }
  out[((size_t)b * TOPK + k) * 2 + 0] = kx;
  out[((size_t)b * TOPK + k) * 2 + 1] = ky;
  out[(size_t)B * TOPK * 2 + (size_t)b * TOPK + k] = sc;
  out[(size_t)B * TOPK * 3 + (size_t)b * TOPK + k] = disp;
}

}  // namespace

extern "C" void kernel_launch(void* const* d_in, const int* in_sizes, int n_in,
                              void* d_out, int out_size, void* d_ws, size_t ws_size,
                              hipStream_t stream) {
  const float* scores = (const float*)d_in[0];
  float* out = (float*)d_out;
  char* ws = (char*)d_ws;

  uint32_t* mask0 = (uint32_t*)(ws + OFF_MASK0);
  uint32_t* mask1 = (uint32_t*)(ws + OFF_MASK1);
  uint32_t* supp  = (uint32_t*)(ws + OFF_SUPP);
  uint32_t* cnt  = (uint32_t*)(ws + OFF_CNT);
  uint32_t* cand_count = cnt;                    // [B]
  uint32_t* sel_count  = cnt + 8;                // [B]
  uint64_t* thr_key    = (uint64_t*)(cnt + 16);  // [B]
  uint64_t* sel  = (uint64_t*)(ws + OFF_SEL);
  uint64_t* topk = (uint64_t*)(ws + OFF_TOPK);
  uint64_t* cand = (uint64_t*)(ws + OFF_CAND);

  hipMemsetAsync(ws + OFF_CNT, 0, 4096, stream);

  dim3 tb(16, 16);
  dim3 tg(W / TSX, H / TSY, B);
  k_mask0<<<tg, tb, 0, stream>>>(scores, mask0);
  k_dilate<<<tg, tb, 0, stream>>>(mask0, supp);                       // supp1
  k_mask_update<<<tg, tb, 0, stream>>>(scores, supp, mask0, mask1);   // mask1
  k_dilate<<<tg, tb, 0, stream>>>(mask1, supp);                       // supp2
  k_emit<<<tg, tb, 0, stream>>>(scores, supp, mask1, cand, cand_count);

  k_select<<<B, 1024, 0, stream>>>(cand, cand_count, thr_key);
  k_compact<<<dim3(CAND_CAP / 1024, B), 1024, 0, stream>>>(cand, cand_count, thr_key, sel, sel_count);
  k_rank<<<dim3(SEL_CAP / 1024, B), 1024, 0, stream>>>(sel, sel_count, topk);
  k_refine<<<(B * TOPK + 255) / 256, 256, 0, stream>>>(scores, topk, out);
}

// Round 4
// 360.060 us; speedup vs baseline: 5.8481x; 1.1202x over previous
//
#include <hip/hip_runtime.h>
#include <stdint.h>

namespace {

constexpr int B = 8;
constexpr int H = 1024;
constexpr int W = 1024;
constexpr int TOPK = 4096;
constexpr int CAND_CAP = 131072;  // per batch
constexpr int SEL_CAP = 8192;     // per batch
constexpr int LIST_CAP = 512;     // per 64x64 tile (spacing>=3 => <=~484 incl ties)

// fused-NMS tile geometry: 64x64 interior, radius-10 halo staged (+2 slack for
// word alignment) => 88x88 staged. Validity shrinks 2 px per in-LDS stage:
// sc[-12,76) -> mask0[-10,74) -> supp1[-8,72) -> h1[-6,70) -> mask1[-4,68)
// -> supp2[-2,66) -> newmax2[0,64) = exact interior.
constexpr int RROWS = 88;   // staged rows
constexpr int NG = 22;      // staged float4 col-groups (88 cols)
constexpr int STR = 92;     // sc row stride (floats): mult of 4 for b128 align
constexpr int MSTR = 23;    // mask row stride (words, odd -> bank friendly)
constexpr int NUNIT = 264;  // 22 groups x 12 row-strips (7 rows each -> rows [2,86))

// workspace layout (bytes)
constexpr size_t OFF_CNT  = 0;                                   // 4 KiB counters
constexpr size_t OFF_SEL  = 4096;                                // B*SEL_CAP*8 = 512 KiB
constexpr size_t OFF_TOPK = OFF_SEL + (size_t)B * SEL_CAP * 8;   // 256 KiB
constexpr size_t OFF_CAND = OFF_TOPK + (size_t)B * TOPK * 8;     // 8 MiB

__device__ __forceinline__ float max5(float a, float b, float c, float d, float e) {
  return fmaxf(fmaxf(fmaxf(a, b), fmaxf(c, d)), e);
}
__device__ __forceinline__ float4 ld4(const float* p) {
  return *reinterpret_cast<const float4*>(p);
}

// mask words: 4 px per u32, one bit per byte (bits 0,8,16,24).
__device__ __forceinline__ uint32_t spread3(uint32_t w0, uint32_t w1, uint32_t w2) {
  unsigned long long a = (unsigned long long)w0 | ((unsigned long long)w1 << 32);
  unsigned long long c = (unsigned long long)w1 | ((unsigned long long)w2 << 32);
  unsigned long long A = a | (a >> 8) | (a >> 16) | (a >> 24) | (a >> 32);
  unsigned long long C = c | (c >> 8) | (c >> 16) | (c >> 24) | (c >> 32);
  return (uint32_t)(((A >> 16) & 0xFFFFull) | ((C & 0xFFFFull) << 16));
}

// One "unit": col-group G in [0,22), row strip s in [0,12) producing staged rows
// r0..r0+6 (r0 = 2+7s). Sliding 5-row window over horizontal 5-max in registers.
// PASS 0: mask0 = (sc == max5x5(sc)) & valid           -> MOUT
// PASS 1: mask1 = M0 | (newmax(ss1) & ~SUP)            -> MOUT   (ss = SUP?0:sc)
// PASS 2: final = M1 | (newmax(ss2) & ~SUP); emit keys
template <int PASS>
__device__ __forceinline__ void score_pass(
    int u, int x0, int y0, const float* __restrict__ S,
    const uint32_t* __restrict__ SUP, const uint32_t* __restrict__ M0,
    uint32_t* __restrict__ MOUT, const uint32_t* __restrict__ M1,
    uint64_t* list, uint32_t* cnt_loc, uint64_t* cand, uint32_t* cand_count, int b) {
  const int G = u % NG;
  const int s = u / NG;
  const int r0 = 2 + 7 * s;
  const int gx0 = x0 - 12 + 4 * G;
  uint32_t colm = 0;
#pragma unroll
  for (int j = 0; j < 4; ++j)
    if ((unsigned)(gx0 + j) < (unsigned)W) colm |= 1u << (8 * j);

  float4 hw[5], cw[5];
#pragma unroll
  for (int k = 0; k < 11; ++k) {
    const int rr = r0 - 2 + k;
    const float* rowp = S + rr * STR + 4 * G;
    float4 d = ld4(rowp);
    float4 a = (G > 0) ? ld4(rowp - 4) : d;     // edge subst: garbage-only positions
    float4 e = (G < NG - 1) ? ld4(rowp + 4) : d;
    if (PASS != 0) {
      const uint32_t* srow = SUP + rr * MSTR;
      uint32_t wD = srow[G];
      uint32_t wA = (G > 0) ? srow[G - 1] : 0u;
      uint32_t wE = (G < NG - 1) ? srow[G + 1] : 0u;
      if (wA & 0x1u) a.x = 0.f;
      if (wA & 0x100u) a.y = 0.f;
      if (wA & 0x10000u) a.z = 0.f;
      if (wA & 0x1000000u) a.w = 0.f;
      if (wD & 0x1u) d.x = 0.f;
      if (wD & 0x100u) d.y = 0.f;
      if (wD & 0x10000u) d.z = 0.f;
      if (wD & 0x1000000u) d.w = 0.f;
      if (wE & 0x1u) e.x = 0.f;
      if (wE & 0x100u) e.y = 0.f;
      if (wE & 0x10000u) e.z = 0.f;
      if (wE & 0x1000000u) e.w = 0.f;
    }
    float4 hm;
    hm.x = max5(a.z, a.w, d.x, d.y, d.z);
    hm.y = max5(a.w, d.x, d.y, d.z, d.w);
    hm.z = max5(d.x, d.y, d.z, d.w, e.x);
    hm.w = max5(d.y, d.z, d.w, e.x, e.y);
    hw[k % 5] = hm;
    cw[k % 5] = d;
    if (k >= 4) {
      const int rq = r0 + k - 4;
      float4 vm;  // max over all 5 ring slots (order-independent)
      vm.x = max5(hw[0].x, hw[1].x, hw[2].x, hw[3].x, hw[4].x);
      vm.y = max5(hw[0].y, hw[1].y, hw[2].y, hw[3].y, hw[4].y);
      vm.z = max5(hw[0].z, hw[1].z, hw[2].z, hw[3].z, hw[4].z);
      vm.w = max5(hw[0].w, hw[1].w, hw[2].w, hw[3].w, hw[4].w);
      float4 c = cw[(k - 2) % 5];  // center row rq (masked value for PASS 1/2)
      const int gy = y0 - 12 + rq;
      uint32_t nm = ((uint32_t)(c.x == vm.x)) | ((uint32_t)(c.y == vm.y) << 8) |
                    ((uint32_t)(c.z == vm.z) << 16) | ((uint32_t)(c.w == vm.w) << 24);
      nm &= ((unsigned)gy < (unsigned)H) ? colm : 0u;  // in-image only
      if (PASS == 0) {
        MOUT[rq * MSTR + G] = nm;
      } else if (PASS == 1) {
        uint32_t sw = SUP[rq * MSTR + G];
        MOUT[rq * MSTR + G] = M0[rq * MSTR + G] | (nm & ~sw);
      } else {
        uint32_t sw = SUP[rq * MSTR + G];
        uint32_t fin = M1[rq * MSTR + G] | (nm & ~sw);
        // interior of this tile: G in [3,19) covers cols [0,64), rq in [12,76)
        if (fin && G >= 3 && G < 19 && rq >= 12 && rq < 76 && gy >= 2 && gy < H - 2) {
#pragma unroll
          for (int j = 0; j < 4; ++j) {
            if ((fin >> (8 * j)) & 1u) {
              int gx = gx0 + j;
              if (gx >= 2 && gx < W - 2) {
                float sval = S[rq * STR + 4 * G + j];  // original (unmasked) score
                if (sval > 0.0f) {
                  uint32_t bits = __float_as_uint(sval);
                  uint32_t flat = (uint32_t)(gy * W + gx);
                  uint64_t key = ((uint64_t)bits << 32) | (uint64_t)(0xFFFFFFFFu - flat);
                  uint32_t pos = atomicAdd(cnt_loc, 1u);
                  if (pos < (uint32_t)LIST_CAP) {
                    list[pos] = key;
                  } else {  // pathological tie overflow: direct global append
                    uint32_t p = atomicAdd(&cand_count[b], 1u);
                    if (p < (uint32_t)CAND_CAP) cand[(size_t)b * CAND_CAP + p] = key;
                  }
                }
              }
            }
          }
        }
      }
    }
  }
}

// bit-dilate r=2: SOUT = any(MIN in 5x5) & valid
__device__ __forceinline__ void dilate_pass(int u, int x0, int y0,
                                            const uint32_t* __restrict__ MIN_,
                                            uint32_t* __restrict__ SOUT) {
  const int G = u % NG;
  const int s = u / NG;
  const int r0 = 2 + 7 * s;
  const int gx0 = x0 - 12 + 4 * G;
  uint32_t colm = 0;
#pragma unroll
  for (int j = 0; j < 4; ++j)
    if ((unsigned)(gx0 + j) < (unsigned)W) colm |= 1u << (8 * j);
  uint32_t ring[5];
#pragma unroll
  for (int k = 0; k < 11; ++k) {
    const int rr = r0 - 2 + k;
    const uint32_t* mrow = MIN_ + rr * MSTR;
    uint32_t w1 = mrow[G];
    uint32_t w0 = (G > 0) ? mrow[G - 1] : 0u;
    uint32_t w2 = (G < NG - 1) ? mrow[G + 1] : 0u;
    ring[k % 5] = spread3(w0, w1, w2);
    if (k >= 4) {
      const int rq = r0 + k - 4;
      uint32_t o = ring[0] | ring[1] | ring[2] | ring[3] | ring[4];
      const int gy = y0 - 12 + rq;
      SOUT[rq * MSTR + G] = ((unsigned)gy < (unsigned)H) ? (o & colm) : 0u;
    }
  }
}

// ---------------- fused 5-pass NMS + candidate emit ----------------------------------
__global__ void __launch_bounds__(256) k_nms(const float* __restrict__ scores,
                                             uint64_t* __restrict__ cand,
                                             uint32_t* __restrict__ cand_count) {
  __shared__ float S[RROWS * STR];          // 32.4 KB staged scores (kept intact)
  __shared__ uint32_t M0s[RROWS * MSTR];    // 8.1 KB
  __shared__ uint32_t SUPs[RROWS * MSTR];   // 8.1 KB (supp1 then supp2)
  __shared__ uint32_t M1s[RROWS * MSTR];    // 8.1 KB
  __shared__ uint64_t list[LIST_CAP];       // 4 KB
  __shared__ uint32_t cnt_loc, base_g;
  const int b = blockIdx.z;
  const int x0 = blockIdx.x * 64, y0 = blockIdx.y * 64;
  const int tid = threadIdx.x;
  const float* img = scores + (size_t)b * H * W;
  if (tid == 0) cnt_loc = 0;

  // stage scores (-inf outside image)
  for (int u = tid; u < RROWS * NG; u += 256) {
    int r = u / NG, G = u % NG;
    int gy = y0 - 12 + r, gx = x0 - 12 + 4 * G;  // gx mult of 4: group all-in or all-out
    float4 v;
    if ((unsigned)gy < (unsigned)H && (unsigned)gx < (unsigned)W)
      v = ld4(img + (size_t)gy * W + gx);
    else
      v = make_float4(-INFINITY, -INFINITY, -INFINITY, -INFINITY);
    *reinterpret_cast<float4*>(&S[r * STR + 4 * G]) = v;
  }
  __syncthreads();
  for (int u = tid; u < NUNIT; u += 256)
    score_pass<0>(u, x0, y0, S, nullptr, nullptr, M0s, nullptr, nullptr, nullptr,
                  nullptr, nullptr, b);
  __syncthreads();
  for (int u = tid; u < NUNIT; u += 256) dilate_pass(u, x0, y0, M0s, SUPs);
  __syncthreads();
  for (int u = tid; u < NUNIT; u += 256)
    score_pass<1>(u, x0, y0, S, SUPs, M0s, M1s, nullptr, nullptr, nullptr, nullptr,
                  nullptr, b);
  __syncthreads();
  for (int u = tid; u < NUNIT; u += 256) dilate_pass(u, x0, y0, M1s, SUPs);
  __syncthreads();
  for (int u = tid; u < NUNIT; u += 256)
    score_pass<2>(u, x0, y0, S, SUPs, nullptr, nullptr, M1s, list, &cnt_loc, cand,
                  cand_count, b);
  __syncthreads();
  uint32_t nblk = cnt_loc;
  uint32_t nmain = nblk < (uint32_t)LIST_CAP ? nblk : (uint32_t)LIST_CAP;
  if (tid == 0) base_g = atomicAdd(&cand_count[b], nmain);
  __syncthreads();
  uint32_t bg = base_g;
  for (uint32_t i = tid; i < nmain; i += 256) {
    uint32_t p = bg + i;
    if (p < (uint32_t)CAND_CAP) cand[(size_t)b * CAND_CAP + p] = list[i];
  }
}

// ---------------- two-level radix threshold ------------------------------------------
__global__ void __launch_bounds__(1024) k_select(const uint64_t* __restrict__ cand,
                                                 const uint32_t* __restrict__ cand_count,
                                                 uint64_t* __restrict__ thr_key) {
  __shared__ uint32_t h1[1024];
  __shared__ uint32_t h2[4096];
  __shared__ uint32_t shC;
  __shared__ uint32_t sh_above;
  const int b = blockIdx.x;
  const int t = threadIdx.x;
  uint32_t n = cand_count[b];
  if (n > (uint32_t)CAND_CAP) n = CAND_CAP;
  const uint64_t* cb = cand + (size_t)b * CAND_CAP;

  h1[t] = 0;
  if (t == 0) { shC = 0xFFFFFFFFu; sh_above = 0; }
  __syncthreads();
  for (uint32_t i = t; i < n; i += 1024) atomicAdd(&h1[(uint32_t)(cb[i] >> 54)], 1u);
  __syncthreads();
  for (int d = 1; d < 1024; d <<= 1) {
    uint32_t v = (t + d < 1024) ? h1[t + d] : 0u;
    __syncthreads();
    h1[t] += v;
    __syncthreads();
  }
  if (h1[0] < (uint32_t)TOPK) {
    if (t == 0) thr_key[b] = 0ull;
    return;
  }
  {
    uint32_t mine = h1[t];
    uint32_t nxt = (t + 1 < 1024) ? h1[t + 1] : 0u;
    if (mine >= (uint32_t)TOPK && nxt < (uint32_t)TOPK) { shC = (uint32_t)t; sh_above = nxt; }
  }
  __syncthreads();
  const uint32_t C = shC;
  const uint32_t above = sh_above;
#pragma unroll
  for (int j = 0; j < 4; ++j) h2[t + j * 1024] = 0;
  __syncthreads();
  for (uint32_t i = t; i < n; i += 1024) {
    uint64_t key = cb[i];
    if ((uint32_t)(key >> 54) == C) atomicAdd(&h2[(uint32_t)(key >> 42) & 0xFFFu], 1u);
  }
  __syncthreads();
  for (int d = 1; d < 4096; d <<= 1) {
    uint32_t v[4];
#pragma unroll
    for (int j = 0; j < 4; ++j) {
      int i = t + j * 1024;
      v[j] = (i + d < 4096) ? h2[i + d] : 0u;
    }
    __syncthreads();
#pragma unroll
    for (int j = 0; j < 4; ++j) h2[t + j * 1024] += v[j];
    __syncthreads();
  }
#pragma unroll
  for (int j = 0; j < 4; ++j) {
    int f = t + j * 1024;
    uint32_t cum = above + h2[f];
    uint32_t cumn = (f + 1 < 4096) ? above + h2[f + 1] : above;
    if (cum >= (uint32_t)TOPK && cumn < (uint32_t)TOPK)
      thr_key[b] = ((uint64_t)C << 54) | ((uint64_t)f << 42);
  }
}

// ---------------- compact ------------------------------------------------------------
__global__ void __launch_bounds__(1024) k_compact(const uint64_t* __restrict__ cand,
                                                  const uint32_t* __restrict__ cand_count,
                                                  const uint64_t* __restrict__ thr_key,
                                                  uint64_t* __restrict__ sel,
                                                  uint32_t* __restrict__ sel_count) {
  __shared__ uint64_t list[1024];
  __shared__ uint32_t cnt_loc;
  __shared__ uint32_t base_g;
  const int b = blockIdx.y;
  uint32_t n = cand_count[b];
  if (n > (uint32_t)CAND_CAP) n = CAND_CAP;
  const int tid = threadIdx.x;
  if (tid == 0) cnt_loc = 0;
  __syncthreads();
  uint32_t i = blockIdx.x * 1024 + tid;
  if (i < n) {
    uint64_t key = cand[(size_t)b * CAND_CAP + i];
    if (key >= thr_key[b]) {
      uint32_t pos = atomicAdd(&cnt_loc, 1u);
      list[pos] = key;
    }
  }
  __syncthreads();
  uint32_t nblk = cnt_loc;
  if (tid == 0 && nblk > 0) base_g = atomicAdd(&sel_count[b], nblk);
  __syncthreads();
  if (nblk > 0 && (uint32_t)tid < nblk) {
    uint32_t p = base_g + tid;
    if (p < (uint32_t)SEL_CAP) sel[(size_t)b * SEL_CAP + p] = list[tid];
  }
}

// ---------------- exact ranking (keys distinct => stable JAX top_k order) ------------
__global__ void __launch_bounds__(1024) k_rank(const uint64_t* __restrict__ sel,
                                               const uint32_t* __restrict__ sel_count,
                                               uint64_t* __restrict__ topk) {
  __shared__ uint64_t keys[SEL_CAP];  // 64 KiB
  const int b = blockIdx.y;
  uint32_t n = sel_count[b];
  if (n > (uint32_t)SEL_CAP) n = SEL_CAP;
  uint32_t i0 = blockIdx.x * 1024;
  if (i0 >= n) return;
  const uint64_t* sb = sel + (size_t)b * SEL_CAP;
  for (uint32_t i = threadIdx.x; i < n; i += 1024) keys[i] = sb[i];
  __syncthreads();
  uint32_t me = i0 + threadIdx.x;
  if (me >= n) return;
  uint64_t kme = keys[me];
  uint32_t rank = 0;
  uint32_t i = 0;
  for (; i + 8 <= n; i += 8) {
    rank += (keys[i] > kme);
    rank += (keys[i + 1] > kme);
    rank += (keys[i + 2] > kme);
    rank += (keys[i + 3] > kme);
    rank += (keys[i + 4] > kme);
    rank += (keys[i + 5] > kme);
    rank += (keys[i + 6] > kme);
    rank += (keys[i + 7] > kme);
  }
  for (; i < n; ++i) rank += (keys[i] > kme);
  if (rank < (uint32_t)TOPK) topk[(size_t)b * TOPK + rank] = kme;
}

// ---------------- per-keypoint refinement --------------------------------------------
__global__ void k_refine(const float* __restrict__ scores,
                         const uint64_t* __restrict__ topk,
                         float* __restrict__ out) {
  int gid = blockIdx.x * blockDim.x + threadIdx.x;
  if (gid >= B * TOPK) return;
  const int b = gid / TOPK;
  const int k = gid % TOPK;
  uint64_t key = topk[(size_t)b * TOPK + k];
  uint32_t flat = 0xFFFFFFFFu - (uint32_t)(key & 0xFFFFFFFFull);
  if (flat >= (uint32_t)(H * W)) flat = 0;  // pad-key guard
  const int ix = (int)(flat % W);
  const int iy = (int)(flat / W);
  const float* img = scores + (size_t)b * H * W;

  float patch[25];
  float maxv = -INFINITY;
#pragma unroll
  for (int r = 0; r < 5; ++r) {
#pragma unroll
    for (int c = 0; c < 5; ++c) {
      int y = iy + r - 2, x = ix + c - 2;
      float v = (x >= 0 && x < W && y >= 0 && y < H) ? img[(size_t)y * W + x] : 0.0f;
      patch[r * 5 + c] = v;
      maxv = fmaxf(maxv, v);
    }
  }
  float e[25];
  float sum = 0.0f, sx = 0.0f, sy = 0.0f;
#pragma unroll
  for (int p = 0; p < 25; ++p) {
    float ev = expf((patch[p] - maxv) / 0.1f);
    e[p] = ev;
    sum += ev;
    sx += ev * (float)(p % 5 - 2);
    sy += ev * (float)(p / 5 - 2);
  }
  float rx = sx / sum, ry = sy / sum;
  float disp = 0.0f;
#pragma unroll
  for (int p = 0; p < 25; ++p) {
    float dx = ((float)(p % 5 - 2) - rx) * 0.5f;
    float dy = ((float)(p / 5 - 2) - ry) * 0.5f;
    disp += e[p] * (dx * dx + dy * dy);
  }
  disp /= sum;
  float kx = ((float)ix + rx) / 1023.0f * 2.0f - 1.0f;
  float ky = ((float)iy + ry) / 1023.0f * 2.0f - 1.0f;
  float px = (kx + 1.0f) * 0.5f * 1023.0f;
  float py = (ky + 1.0f) * 0.5f * 1023.0f;
  float x0f = floorf(px), y0f = floorf(py);
  float wx1 = px - x0f, wx0 = 1.0f - wx1;
  float wy1 = py - y0f, wy0 = 1.0f - wy1;
  int x0 = (int)x0f, y0 = (int)y0f;
  float sc = 0.0f;
  {
    int xs[2] = {x0, x0 + 1};
    int ys[2] = {y0, y0 + 1};
    float wxs[2] = {wx0, wx1};
    float wys[2] = {wy0, wy1};
#pragma unroll
    for (int yy = 0; yy < 2; ++yy)
#pragma unroll
      for (int xx = 0; xx < 2; ++xx) {
        int xi = xs[xx], yi = ys[yy];
        bool valid = (xi >= 0 && xi < W && yi >= 0 && yi < H);
        int xc = min(max(xi, 0), W - 1);
        int yc = min(max(yi, 0), H - 1);
        float v = valid ? img[(size_t)yc * W + xc] : 0.0f;
        sc += v * (wxs[xx] * wys[yy]);
      }
  }
  out[((size_t)b * TOPK + k) * 2 + 0] = kx;
  out[((size_t)b * TOPK + k) * 2 + 1] = ky;
  out[(size_t)B * TOPK * 2 + (size_t)b * TOPK + k] = sc;
  out[(size_t)B * TOPK * 3 + (size_t)b * TOPK + k] = disp;
}

}  // namespace

extern "C" void kernel_launch(void* const* d_in, const int* in_sizes, int n_in,
                              void* d_out, int out_size, void* d_ws, size_t ws_size,
                              hipStream_t stream) {
  const float* scores = (const float*)d_in[0];
  float* out = (float*)d_out;
  char* ws = (char*)d_ws;

  uint32_t* cnt = (uint32_t*)(ws + OFF_CNT);
  uint32_t* cand_count = cnt;                    // [B]
  uint32_t* sel_count  = cnt + 8;                // [B]
  uint64_t* thr_key    = (uint64_t*)(cnt + 16);  // [B]
  uint64_t* sel  = (uint64_t*)(ws + OFF_SEL);
  uint64_t* topk = (uint64_t*)(ws + OFF_TOPK);
  uint64_t* cand = (uint64_t*)(ws + OFF_CAND);

  hipMemsetAsync(ws + OFF_CNT, 0, 4096, stream);

  k_nms<<<dim3(W / 64, H / 64, B), 256, 0, stream>>>(scores, cand, cand_count);
  k_select<<<B, 1024, 0, stream>>>(cand, cand_count, thr_key);
  k_compact<<<dim3(CAND_CAP / 1024, B), 1024, 0, stream>>>(cand, cand_count, thr_key, sel, sel_count);
  k_rank<<<dim3(SEL_CAP / 1024, B), 1024, 0, stream>>>(sel, sel_count, topk);
  k_refine<<<(B * TOPK + 255) / 256, 256, 0, stream>>>(scores, topk, out);
}

// Round 5
// 305.729 us; speedup vs baseline: 6.8874x; 1.1777x over previous
//
#include <hip/hip_runtime.h>
#include <stdint.h>

namespace {

constexpr int B = 8;
constexpr int H = 1024;
constexpr int W = 1024;
constexpr int TOPK = 4096;
constexpr int CAND_CAP = 131072;  // per batch
constexpr int SEL_CAP = 8192;     // per batch
constexpr int LIST_CAP = 320;     // per 64x64 tile (avg ~164 survivors, +margin; fallback below)

// fused-NMS tile: 64x64 interior, radius-12 staged halo. Staged rows padded to 92
// (strips write rows 2..89; garbage from pad rows >=88 shrinks 2/stage: mask0>=86,
// supp1>=84, mask1>=82, supp2>=80, final>=78 — interior rows 12..75 untouched).
constexpr int RROWS = 92;   // staged score rows
constexpr int NG = 22;      // float4 col-groups (88 cols)
constexpr int STR = 88;     // score row stride (floats; 352B, 16B-aligned rows)
constexpr int MW4 = 4;      // bitpacked mask words per row (96 bits; word 3 = zero pad)
constexpr int NSTRIP = 11;  // 11 strips x 8 output rows = rows 2..89
constexpr int NUNIT = NG * NSTRIP;  // 242 <= 256: one round per pass, no tail

// workspace layout (bytes)
constexpr size_t OFF_CNT  = 0;                                   // 4 KiB counters
constexpr size_t OFF_SEL  = 4096;                                // B*SEL_CAP*8 = 512 KiB
constexpr size_t OFF_TOPK = OFF_SEL + (size_t)B * SEL_CAP * 8;   // 256 KiB
constexpr size_t OFF_CAND = OFF_TOPK + (size_t)B * TOPK * 8;     // 8 MiB

__device__ __forceinline__ float max5(float a, float b, float c, float d, float e) {
  return fmaxf(fmaxf(fmaxf(a, b), fmaxf(c, d)), e);
}
__device__ __forceinline__ float4 ld4(const float* p) {
  return *reinterpret_cast<const float4*>(p);
}

// One unit: col-group G in [0,22), strip s in [0,11) -> staged rows r0..r0+7 (r0=2+8s).
// Sliding 5-row window of horizontal 5-maxes in registers. Masks bitpacked 1bit/px.
// PASS 0: mask0 = (sc == max5x5(sc)) & valid          -> atomicOr MA
// PASS 1: mask1 = mask0 | (newmax(sup?0:sc) & ~sup1)  -> atomicOr MA (in place)
// PASS 2: final = mask1 | (newmax(sup?0:sc) & ~sup2)  -> emit keys
template <int PASS>
__device__ __forceinline__ void score_pass(
    int u, int x0, int y0, const float* __restrict__ S,
    const uint32_t* __restrict__ SUP, uint32_t* __restrict__ MA,
    uint64_t* list, uint32_t* cnt_loc, uint64_t* cand, uint32_t* cand_count, int b) {
  const int G = u % NG, s = u / NG;
  const int r0 = 2 + 8 * s;
  const int gx0 = x0 - 12 + 4 * G;
  uint32_t colm = 0;
#pragma unroll
  for (int j = 0; j < 4; ++j)
    if ((unsigned)(gx0 + j) < (unsigned)W) colm |= 1u << j;
  // suppression window: bits 0..3 -> cols 4G-4.. (a), 4..7 -> d, 8..11 -> e
  const int p = 4 * G - 4;
  const int pw = (p < 0) ? 0 : (p >> 5);
  const int psh = (p < 0) ? 0 : (p & 31);
  const int pls = (p < 0) ? -p : 0;

  float4 hw[5], cw[5];
  uint32_t sn[5];
#pragma unroll
  for (int k = 0; k < 12; ++k) {
    const int rr = r0 - 2 + k;
    const float* rowp = S + rr * STR + 4 * G;
    float4 d = ld4(rowp);
    float4 a = (G > 0) ? ld4(rowp - 4) : d;     // garbage-only cols, safe
    float4 e = (G < NG - 1) ? ld4(rowp + 4) : d;
    uint32_t supn = 0;
    if (PASS != 0) {
      const uint32_t* srow = SUP + rr * MW4;
      uint64_t X = (uint64_t)srow[pw] | ((uint64_t)srow[pw + 1] << 32);
      uint64_t win = pls ? (X << pls) : (X >> psh);
      if (win & 0x001u) a.x = 0.f;
      if (win & 0x002u) a.y = 0.f;
      if (win & 0x004u) a.z = 0.f;
      if (win & 0x008u) a.w = 0.f;
      if (win & 0x010u) d.x = 0.f;
      if (win & 0x020u) d.y = 0.f;
      if (win & 0x040u) d.z = 0.f;
      if (win & 0x080u) d.w = 0.f;
      if (win & 0x100u) e.x = 0.f;
      if (win & 0x200u) e.y = 0.f;
      if (win & 0x400u) e.z = 0.f;
      if (win & 0x800u) e.w = 0.f;
      supn = (uint32_t)(win >> 4) & 0xFu;
    }
    float4 hm;
    hm.x = max5(a.z, a.w, d.x, d.y, d.z);
    hm.y = max5(a.w, d.x, d.y, d.z, d.w);
    hm.z = max5(d.x, d.y, d.z, d.w, e.x);
    hm.w = max5(d.y, d.z, d.w, e.x, e.y);
    hw[k % 5] = hm;
    cw[k % 5] = d;
    sn[k % 5] = supn;
    if (k >= 4) {
      const int rq = r0 + k - 4;
      const int gy = y0 - 12 + rq;
      float4 vm;
      vm.x = max5(hw[0].x, hw[1].x, hw[2].x, hw[3].x, hw[4].x);
      vm.y = max5(hw[0].y, hw[1].y, hw[2].y, hw[3].y, hw[4].y);
      vm.z = max5(hw[0].z, hw[1].z, hw[2].z, hw[3].z, hw[4].z);
      vm.w = max5(hw[0].w, hw[1].w, hw[2].w, hw[3].w, hw[4].w);
      float4 c = cw[(k + 3) % 5];  // center row rq (masked value for PASS 1/2)
      uint32_t nm = (uint32_t)(c.x == vm.x) | ((uint32_t)(c.y == vm.y) << 1) |
                    ((uint32_t)(c.z == vm.z) << 2) | ((uint32_t)(c.w == vm.w) << 3);
      nm &= ((unsigned)gy < (unsigned)H) ? colm : 0u;
      const int widx = rq * MW4 + (G >> 3);
      const int shift = 4 * (G & 7);
      if (PASS == 0) {
        if (nm) atomicOr(&MA[widx], nm << shift);
      } else if (PASS == 1) {
        uint32_t v = nm & ~sn[(k + 3) % 5];
        if (v) atomicOr(&MA[widx], v << shift);
      } else {
        uint32_t fin = ((MA[widx] >> shift) & 0xFu) | (nm & ~sn[(k + 3) % 5]);
        if (fin && G >= 3 && G < 19 && rq >= 12 && rq < 76 && gy >= 2 && gy < H - 2) {
#pragma unroll
          for (int j = 0; j < 4; ++j) {
            if ((fin >> j) & 1u) {
              int gx = gx0 + j;
              if (gx >= 2 && gx < W - 2) {
                float sval = S[rq * STR + 4 * G + j];  // original (unmasked) score
                if (sval > 0.0f) {
                  uint32_t bits = __float_as_uint(sval);
                  uint32_t flat = (uint32_t)(gy * W + gx);
                  uint64_t key = ((uint64_t)bits << 32) | (uint64_t)(0xFFFFFFFFu - flat);
                  uint32_t pos = atomicAdd(cnt_loc, 1u);
                  if (pos < (uint32_t)LIST_CAP) {
                    list[pos] = key;
                  } else {  // tie overflow: direct global append (rare)
                    uint32_t pp = atomicAdd(&cand_count[b], 1u);
                    if (pp < (uint32_t)CAND_CAP) cand[(size_t)b * CAND_CAP + pp] = key;
                  }
                }
              }
            }
          }
        }
      }
    }
  }
}

// bit-dilate r=2: SOUT |= any(MIN in 5x5) & valid (nibble per (row, G))
__device__ __forceinline__ void dilate_pass(int u, int x0, int y0,
                                            const uint32_t* __restrict__ MIN_,
                                            uint32_t* __restrict__ SOUT) {
  const int G = u % NG, s = u / NG;
  const int r0 = 2 + 8 * s;
  const int gx0 = x0 - 12 + 4 * G;
  uint32_t colm = 0;
#pragma unroll
  for (int j = 0; j < 4; ++j)
    if ((unsigned)(gx0 + j) < (unsigned)W) colm |= 1u << j;
  const int p = 4 * G - 2;  // window bit m = staged col p+m
  const int pw = (p < 0) ? 0 : (p >> 5);
  const int psh = (p < 0) ? 0 : (p & 31);
  const int pls = (p < 0) ? -p : 0;
  uint32_t ring[5];
#pragma unroll
  for (int k = 0; k < 12; ++k) {
    const int rr = r0 - 2 + k;
    const uint32_t* srow = MIN_ + rr * MW4;
    uint64_t X = (uint64_t)srow[pw] | ((uint64_t)srow[pw + 1] << 32);
    uint64_t win = pls ? (X << pls) : (X >> psh);
    uint64_t t = win | (win >> 1) | (win >> 2) | (win >> 3) | (win >> 4);
    ring[k % 5] = (uint32_t)t & 0xFu;
    if (k >= 4) {
      const int rq = r0 + k - 4;
      const int gy = y0 - 12 + rq;
      uint32_t nib = ring[0] | ring[1] | ring[2] | ring[3] | ring[4];
      nib &= ((unsigned)gy < (unsigned)H) ? colm : 0u;
      if (nib) atomicOr(&SOUT[rq * MW4 + (G >> 3)], nib << (4 * (G & 7)));
    }
  }
}

// ---------------- fused 5-pass NMS + candidate emit ----------------------------------
__global__ void __launch_bounds__(256, 4) k_nms(const float* __restrict__ scores,
                                                uint64_t* __restrict__ cand,
                                                uint32_t* __restrict__ cand_count) {
  __shared__ float S[RROWS * STR];        // 32.4 KB
  __shared__ uint32_t MAs[RROWS * MW4];   // 1.47 KB (mask0, then mask1 in place)
  __shared__ uint32_t SP1[RROWS * MW4];   // 1.47 KB
  __shared__ uint32_t SP2[RROWS * MW4];   // 1.47 KB
  __shared__ uint64_t list[LIST_CAP];     // 2.5 KB
  __shared__ uint32_t cnt_loc, base_g;
  const int b = blockIdx.z;
  const int x0 = blockIdx.x * 64, y0 = blockIdx.y * 64;
  const int tid = threadIdx.x;
  const float* img = scores + (size_t)b * H * W;
  if (tid == 0) cnt_loc = 0;

  for (int u = tid; u < RROWS * NG; u += 256) {
    int r = u / NG, G = u % NG;
    int gy = y0 - 12 + r, gx = x0 - 12 + 4 * G;
    float4 v;
    if ((unsigned)gy < (unsigned)H && (unsigned)gx < (unsigned)W)
      v = ld4(img + (size_t)gy * W + gx);
    else
      v = make_float4(-INFINITY, -INFINITY, -INFINITY, -INFINITY);
    *reinterpret_cast<float4*>(&S[r * STR + 4 * G]) = v;
  }
  for (int i = tid; i < RROWS * MW4; i += 256) {
    MAs[i] = 0;
    SP1[i] = 0;
    SP2[i] = 0;
  }
  __syncthreads();
  if (tid < NUNIT)
    score_pass<0>(tid, x0, y0, S, nullptr, MAs, nullptr, nullptr, nullptr, nullptr, b);
  __syncthreads();
  if (tid < NUNIT) dilate_pass(tid, x0, y0, MAs, SP1);
  __syncthreads();
  if (tid < NUNIT)
    score_pass<1>(tid, x0, y0, S, SP1, MAs, nullptr, nullptr, nullptr, nullptr, b);
  __syncthreads();
  if (tid < NUNIT) dilate_pass(tid, x0, y0, MAs, SP2);
  __syncthreads();
  if (tid < NUNIT)
    score_pass<2>(tid, x0, y0, S, SP2, MAs, list, &cnt_loc, cand, cand_count, b);
  __syncthreads();
  uint32_t nblk = cnt_loc;
  uint32_t nmain = nblk < (uint32_t)LIST_CAP ? nblk : (uint32_t)LIST_CAP;
  if (tid == 0) base_g = atomicAdd(&cand_count[b], nmain);
  __syncthreads();
  uint32_t bg = base_g;
  for (uint32_t i = tid; i < nmain; i += 256) {
    uint32_t pp = bg + i;
    if (pp < (uint32_t)CAND_CAP) cand[(size_t)b * CAND_CAP + pp] = list[i];
  }
}

// ---------------- two-level radix threshold ------------------------------------------
__global__ void __launch_bounds__(1024) k_select(const uint64_t* __restrict__ cand,
                                                 const uint32_t* __restrict__ cand_count,
                                                 uint64_t* __restrict__ thr_key) {
  __shared__ uint32_t h1[1024];
  __shared__ uint32_t h2[4096];
  __shared__ uint32_t shC;
  __shared__ uint32_t sh_above;
  const int b = blockIdx.x;
  const int t = threadIdx.x;
  uint32_t n = cand_count[b];
  if (n > (uint32_t)CAND_CAP) n = CAND_CAP;
  const uint64_t* cb = cand + (size_t)b * CAND_CAP;

  h1[t] = 0;
  if (t == 0) { shC = 0xFFFFFFFFu; sh_above = 0; }
  __syncthreads();
  for (uint32_t i = t; i < n; i += 1024) atomicAdd(&h1[(uint32_t)(cb[i] >> 54)], 1u);
  __syncthreads();
  for (int d = 1; d < 1024; d <<= 1) {
    uint32_t v = (t + d < 1024) ? h1[t + d] : 0u;
    __syncthreads();
    h1[t] += v;
    __syncthreads();
  }
  if (h1[0] < (uint32_t)TOPK) {
    if (t == 0) thr_key[b] = 0ull;
    return;
  }
  {
    uint32_t mine = h1[t];
    uint32_t nxt = (t + 1 < 1024) ? h1[t + 1] : 0u;
    if (mine >= (uint32_t)TOPK && nxt < (uint32_t)TOPK) { shC = (uint32_t)t; sh_above = nxt; }
  }
  __syncthreads();
  const uint32_t C = shC;
  const uint32_t above = sh_above;
#pragma unroll
  for (int j = 0; j < 4; ++j) h2[t + j * 1024] = 0;
  __syncthreads();
  for (uint32_t i = t; i < n; i += 1024) {
    uint64_t key = cb[i];
    if ((uint32_t)(key >> 54) == C) atomicAdd(&h2[(uint32_t)(key >> 42) & 0xFFFu], 1u);
  }
  __syncthreads();
  for (int d = 1; d < 4096; d <<= 1) {
    uint32_t v[4];
#pragma unroll
    for (int j = 0; j < 4; ++j) {
      int i = t + j * 1024;
      v[j] = (i + d < 4096) ? h2[i + d] : 0u;
    }
    __syncthreads();
#pragma unroll
    for (int j = 0; j < 4; ++j) h2[t + j * 1024] += v[j];
    __syncthreads();
  }
#pragma unroll
  for (int j = 0; j < 4; ++j) {
    int f = t + j * 1024;
    uint32_t cum = above + h2[f];
    uint32_t cumn = (f + 1 < 4096) ? above + h2[f + 1] : above;
    if (cum >= (uint32_t)TOPK && cumn < (uint32_t)TOPK)
      thr_key[b] = ((uint64_t)C << 54) | ((uint64_t)f << 42);
  }
}

// ---------------- compact ------------------------------------------------------------
__global__ void __launch_bounds__(1024) k_compact(const uint64_t* __restrict__ cand,
                                                  const uint32_t* __restrict__ cand_count,
                                                  const uint64_t* __restrict__ thr_key,
                                                  uint64_t* __restrict__ sel,
                                                  uint32_t* __restrict__ sel_count) {
  __shared__ uint64_t list[1024];
  __shared__ uint32_t cnt_loc;
  __shared__ uint32_t base_g;
  const int b = blockIdx.y;
  uint32_t n = cand_count[b];
  if (n > (uint32_t)CAND_CAP) n = CAND_CAP;
  const int tid = threadIdx.x;
  if (tid == 0) cnt_loc = 0;
  __syncthreads();
  uint32_t i = blockIdx.x * 1024 + tid;
  if (i < n) {
    uint64_t key = cand[(size_t)b * CAND_CAP + i];
    if (key >= thr_key[b]) {
      uint32_t pos = atomicAdd(&cnt_loc, 1u);
      list[pos] = key;
    }
  }
  __syncthreads();
  uint32_t nblk = cnt_loc;
  if (tid == 0 && nblk > 0) base_g = atomicAdd(&sel_count[b], nblk);
  __syncthreads();
  if (nblk > 0 && (uint32_t)tid < nblk) {
    uint32_t pp = base_g + tid;
    if (pp < (uint32_t)SEL_CAP) sel[(size_t)b * SEL_CAP + pp] = list[tid];
  }
}

// ---------------- exact ranking (keys distinct => stable JAX top_k order) ------------
__global__ void __launch_bounds__(1024) k_rank(const uint64_t* __restrict__ sel,
                                               const uint32_t* __restrict__ sel_count,
                                               uint64_t* __restrict__ topk) {
  __shared__ uint64_t keys[SEL_CAP];  // 64 KiB
  const int b = blockIdx.y;
  uint32_t n = sel_count[b];
  if (n > (uint32_t)SEL_CAP) n = SEL_CAP;
  uint32_t i0 = blockIdx.x * 1024;
  if (i0 >= n) return;
  const uint64_t* sb = sel + (size_t)b * SEL_CAP;
  for (uint32_t i = threadIdx.x; i < n; i += 1024) keys[i] = sb[i];
  __syncthreads();
  uint32_t me = i0 + threadIdx.x;
  if (me >= n) return;
  uint64_t kme = keys[me];
  uint32_t rank = 0;
  uint32_t i = 0;
  for (; i + 8 <= n; i += 8) {
    rank += (keys[i] > kme);
    rank += (keys[i + 1] > kme);
    rank += (keys[i + 2] > kme);
    rank += (keys[i + 3] > kme);
    rank += (keys[i + 4] > kme);
    rank += (keys[i + 5] > kme);
    rank += (keys[i + 6] > kme);
    rank += (keys[i + 7] > kme);
  }
  for (; i < n; ++i) rank += (keys[i] > kme);
  if (rank < (uint32_t)TOPK) topk[(size_t)b * TOPK + rank] = kme;
}

// ---------------- refinement: 8 lanes per keypoint -----------------------------------
__global__ void __launch_bounds__(256) k_refine(const float* __restrict__ scores,
                                                const uint64_t* __restrict__ topk,
                                                float* __restrict__ out) {
  int gid = blockIdx.x * 256 + threadIdx.x;
  int kp = gid >> 3, ln = gid & 7;
  const int b = kp / TOPK;
  const int k = kp % TOPK;
  uint64_t key = topk[(size_t)b * TOPK + k];
  uint32_t flat = 0xFFFFFFFFu - (uint32_t)(key & 0xFFFFFFFFull);
  if (flat >= (uint32_t)(H * W)) flat = 0;  // pad-key guard
  const int ix = (int)(flat % W);
  const int iy = (int)(flat / W);
  const float* img = scores + (size_t)b * H * W;

  // lane ln handles taps ln, ln+8, ln+16 (+ tap 24 for ln==0)
  const int nt = (ln == 0) ? 4 : 3;
  float v[4];
  float mymax = -INFINITY;
#pragma unroll
  for (int i = 0; i < 4; ++i) {
    if (i < nt) {
      int t = ln + 8 * i;
      int y = iy + t / 5 - 2, x = ix + t % 5 - 2;
      float val = ((unsigned)x < (unsigned)W && (unsigned)y < (unsigned)H)
                      ? img[(size_t)y * W + x] : 0.0f;
      v[i] = val;
      mymax = fmaxf(mymax, val);
    }
  }
#pragma unroll
  for (int m = 1; m < 8; m <<= 1) mymax = fmaxf(mymax, __shfl_xor(mymax, m));
  float e[4];
  float sum = 0.f, sx = 0.f, sy = 0.f;
#pragma unroll
  for (int i = 0; i < 4; ++i) {
    if (i < nt) {
      int t = ln + 8 * i;
      float ev = expf((v[i] - mymax) / 0.1f);
      e[i] = ev;
      sum += ev;
      sx += ev * (float)(t % 5 - 2);
      sy += ev * (float)(t / 5 - 2);
    }
  }
#pragma unroll
  for (int m = 1; m < 8; m <<= 1) {
    sum += __shfl_xor(sum, m);
    sx += __shfl_xor(sx, m);
    sy += __shfl_xor(sy, m);
  }
  float rx = sx / sum, ry = sy / sum;
  float dsp = 0.f;
#pragma unroll
  for (int i = 0; i < 4; ++i) {
    if (i < nt) {
      int t = ln + 8 * i;
      float dx = ((float)(t % 5 - 2) - rx) * 0.5f;
      float dy = ((float)(t / 5 - 2) - ry) * 0.5f;
      dsp += e[i] * (dx * dx + dy * dy);
    }
  }
#pragma unroll
  for (int m = 1; m < 8; m <<= 1) dsp += __shfl_xor(dsp, m);
  if (ln != 0) return;
  dsp /= sum;
  float kx = ((float)ix + rx) / 1023.0f * 2.0f - 1.0f;
  float ky = ((float)iy + ry) / 1023.0f * 2.0f - 1.0f;
  float px = (kx + 1.0f) * 0.5f * 1023.0f;
  float py = (ky + 1.0f) * 0.5f * 1023.0f;
  float x0f = floorf(px), y0f = floorf(py);
  float wx1 = px - x0f, wx0 = 1.0f - wx1;
  float wy1 = py - y0f, wy0 = 1.0f - wy1;
  int x0 = (int)x0f, y0 = (int)y0f;
  float sc = 0.0f;
  {
    int xs[2] = {x0, x0 + 1};
    int ys[2] = {y0, y0 + 1};
    float wxs[2] = {wx0, wx1};
    float wys[2] = {wy0, wy1};
#pragma unroll
    for (int yy = 0; yy < 2; ++yy)
#pragma unroll
      for (int xx = 0; xx < 2; ++xx) {
        int xi = xs[xx], yi = ys[yy];
        bool valid = (xi >= 0 && xi < W && yi >= 0 && yi < H);
        int xc = min(max(xi, 0), W - 1);
        int yc = min(max(yi, 0), H - 1);
        float vv = valid ? img[(size_t)yc * W + xc] : 0.0f;
        sc += vv * (wxs[xx] * wys[yy]);
      }
  }
  out[((size_t)b * TOPK + k) * 2 + 0] = kx;
  out[((size_t)b * TOPK + k) * 2 + 1] = ky;
  out[(size_t)B * TOPK * 2 + (size_t)b * TOPK + k] = sc;
  out[(size_t)B * TOPK * 3 + (size_t)b * TOPK + k] = dsp;
}

}  // namespace

extern "C" void kernel_launch(void* const* d_in, const int* in_sizes, int n_in,
                              void* d_out, int out_size, void* d_ws, size_t ws_size,
                              hipStream_t stream) {
  const float* scores = (const float*)d_in[0];
  float* out = (float*)d_out;
  char* ws = (char*)d_ws;

  uint32_t* cnt = (uint32_t*)(ws + OFF_CNT);
  uint32_t* cand_count = cnt;                    // [B]
  uint32_t* sel_count  = cnt + 8;                // [B]
  uint64_t* thr_key    = (uint64_t*)(cnt + 16);  // [B]
  uint64_t* sel  = (uint64_t*)(ws + OFF_SEL);
  uint64_t* topk = (uint64_t*)(ws + OFF_TOPK);
  uint64_t* cand = (uint64_t*)(ws + OFF_CAND);

  hipMemsetAsync(ws + OFF_CNT, 0, 4096, stream);

  k_nms<<<dim3(W / 64, H / 64, B), 256, 0, stream>>>(scores, cand, cand_count);
  k_select<<<B, 1024, 0, stream>>>(cand, cand_count, thr_key);
  k_compact<<<dim3(CAND_CAP / 1024, B), 1024, 0, stream>>>(cand, cand_count, thr_key, sel, sel_count);
  k_rank<<<dim3(SEL_CAP / 1024, B), 1024, 0, stream>>>(sel, sel_count, topk);
  k_refine<<<(B * TOPK * 8) / 256, 256, 0, stream>>>(scores, topk, out);
}

// Round 6
// 258.825 us; speedup vs baseline: 8.1355x; 1.1812x over previous
//
#include <hip/hip_runtime.h>
#include <stdint.h>

namespace {

constexpr int B = 8;
constexpr int H = 1024;
constexpr int W = 1024;
constexpr int TOPK = 4096;
constexpr int CAND_CAP = 131072;  // per batch
constexpr int SEL_CAP = 8192;     // per batch
constexpr int LIST_CAP = 320;     // per 64x64 tile (avg ~164 survivors; fallback below)

// fused-NMS tile: 64x64 interior, radius-12 staged halo. Staged rows padded to 92
// (strips write rows 2..89; garbage from pad rows >=88 shrinks 2/stage: mask0>=86,
// supp1>=84, mask1>=82, supp2>=80, final>=78 — interior rows 12..75 untouched).
constexpr int RROWS = 92;   // staged score rows
constexpr int NG = 22;      // float4 col-groups (88 cols)
constexpr int STR = 88;     // score row stride (floats; 352B, 16B-aligned rows)
constexpr int MW4 = 4;      // bitpacked mask words per row (96 bits; word 3 = zero pad)
constexpr int NSTRIP = 11;  // 11 strips x 8 output rows = rows 2..89
constexpr int NUNIT = NG * NSTRIP;  // 242 <= 256: one round per pass, no tail

// rank kernel tiling
constexpr int RK_ME = 256;    // me-keys per block (1/thread)
constexpr int RK_CH = 1024;   // chunk keys staged in LDS per block

// workspace layout (bytes)
constexpr size_t OFF_CNT  = 0;                                   // 4 KiB counters
constexpr size_t OFF_RANK = 4096;                                // B*SEL_CAP*4 = 256 KiB
constexpr size_t OFF_SEL  = OFF_RANK + (size_t)B * SEL_CAP * 4;  // 512 KiB
constexpr size_t OFF_TOPK = OFF_SEL + (size_t)B * SEL_CAP * 8;   // 256 KiB
constexpr size_t OFF_CAND = OFF_TOPK + (size_t)B * TOPK * 8;     // 8 MiB
constexpr size_t MEMSET_BYTES = 4096 + (size_t)B * SEL_CAP * 4;  // cnt + rank

__device__ __forceinline__ float max5(float a, float b, float c, float d, float e) {
  return fmaxf(fmaxf(fmaxf(a, b), fmaxf(c, d)), e);
}
__device__ __forceinline__ float4 ld4(const float* p) {
  return *reinterpret_cast<const float4*>(p);
}

// One unit: col-group G in [0,22), strip s in [0,11) -> staged rows r0..r0+7 (r0=2+8s).
// Sliding 5-row window of horizontal 5-maxes in registers. Masks bitpacked 1bit/px.
template <int PASS>
__device__ __forceinline__ void score_pass(
    int u, int x0, int y0, const float* __restrict__ S,
    const uint32_t* __restrict__ SUP, uint32_t* __restrict__ MA,
    uint64_t* list, uint32_t* cnt_loc, uint64_t* cand, uint32_t* cand_count, int b) {
  const int G = u % NG, s = u / NG;
  const int r0 = 2 + 8 * s;
  const int gx0 = x0 - 12 + 4 * G;
  uint32_t colm = 0;
#pragma unroll
  for (int j = 0; j < 4; ++j)
    if ((unsigned)(gx0 + j) < (unsigned)W) colm |= 1u << j;
  const int p = 4 * G - 4;
  const int pw = (p < 0) ? 0 : (p >> 5);
  const int psh = (p < 0) ? 0 : (p & 31);
  const int pls = (p < 0) ? -p : 0;

  float4 hw[5], cw[5];
  uint32_t sn[5];
#pragma unroll
  for (int k = 0; k < 12; ++k) {
    const int rr = r0 - 2 + k;
    const float* rowp = S + rr * STR + 4 * G;
    float4 d = ld4(rowp);
    float4 a = (G > 0) ? ld4(rowp - 4) : d;  // garbage-only cols, safe
    float4 e = (G < NG - 1) ? ld4(rowp + 4) : d;
    uint32_t supn = 0;
    if (PASS != 0) {
      const uint32_t* srow = SUP + rr * MW4;
      uint64_t X = (uint64_t)srow[pw] | ((uint64_t)srow[pw + 1] << 32);
      uint64_t win = pls ? (X << pls) : (X >> psh);
      if (win & 0x001u) a.x = 0.f;
      if (win & 0x002u) a.y = 0.f;
      if (win & 0x004u) a.z = 0.f;
      if (win & 0x008u) a.w = 0.f;
      if (win & 0x010u) d.x = 0.f;
      if (win & 0x020u) d.y = 0.f;
      if (win & 0x040u) d.z = 0.f;
      if (win & 0x080u) d.w = 0.f;
      if (win & 0x100u) e.x = 0.f;
      if (win & 0x200u) e.y = 0.f;
      if (win & 0x400u) e.z = 0.f;
      if (win & 0x800u) e.w = 0.f;
      supn = (uint32_t)(win >> 4) & 0xFu;
    }
    float4 hm;
    hm.x = max5(a.z, a.w, d.x, d.y, d.z);
    hm.y = max5(a.w, d.x, d.y, d.z, d.w);
    hm.z = max5(d.x, d.y, d.z, d.w, e.x);
    hm.w = max5(d.y, d.z, d.w, e.x, e.y);
    hw[k % 5] = hm;
    cw[k % 5] = d;
    sn[k % 5] = supn;
    if (k >= 4) {
      const int rq = r0 + k - 4;
      const int gy = y0 - 12 + rq;
      float4 vm;
      vm.x = max5(hw[0].x, hw[1].x, hw[2].x, hw[3].x, hw[4].x);
      vm.y = max5(hw[0].y, hw[1].y, hw[2].y, hw[3].y, hw[4].y);
      vm.z = max5(hw[0].z, hw[1].z, hw[2].z, hw[3].z, hw[4].z);
      vm.w = max5(hw[0].w, hw[1].w, hw[2].w, hw[3].w, hw[4].w);
      float4 c = cw[(k + 3) % 5];  // center row rq (masked value for PASS 1/2)
      uint32_t nm = (uint32_t)(c.x == vm.x) | ((uint32_t)(c.y == vm.y) << 1) |
                    ((uint32_t)(c.z == vm.z) << 2) | ((uint32_t)(c.w == vm.w) << 3);
      nm &= ((unsigned)gy < (unsigned)H) ? colm : 0u;
      const int widx = rq * MW4 + (G >> 3);
      const int shift = 4 * (G & 7);
      if (PASS == 0) {
        if (nm) atomicOr(&MA[widx], nm << shift);
      } else if (PASS == 1) {
        uint32_t v = nm & ~sn[(k + 3) % 5];
        if (v) atomicOr(&MA[widx], v << shift);
      } else {
        uint32_t fin = ((MA[widx] >> shift) & 0xFu) | (nm & ~sn[(k + 3) % 5]);
        if (fin && G >= 3 && G < 19 && rq >= 12 && rq < 76 && gy >= 2 && gy < H - 2) {
#pragma unroll
          for (int j = 0; j < 4; ++j) {
            if ((fin >> j) & 1u) {
              int gx = gx0 + j;
              if (gx >= 2 && gx < W - 2) {
                float sval = S[rq * STR + 4 * G + j];  // original (unmasked) score
                if (sval > 0.0f) {
                  uint32_t bits = __float_as_uint(sval);
                  uint32_t flat = (uint32_t)(gy * W + gx);
                  uint64_t key = ((uint64_t)bits << 32) | (uint64_t)(0xFFFFFFFFu - flat);
                  uint32_t pos = atomicAdd(cnt_loc, 1u);
                  if (pos < (uint32_t)LIST_CAP) {
                    list[pos] = key;
                  } else {  // tie overflow: direct global append (rare)
                    uint32_t pp = atomicAdd(&cand_count[b], 1u);
                    if (pp < (uint32_t)CAND_CAP) cand[(size_t)b * CAND_CAP + pp] = key;
                  }
                }
              }
            }
          }
        }
      }
    }
  }
}

// bit-dilate r=2: SOUT |= any(MIN in 5x5) & valid (nibble per (row, G))
__device__ __forceinline__ void dilate_pass(int u, int x0, int y0,
                                            const uint32_t* __restrict__ MIN_,
                                            uint32_t* __restrict__ SOUT) {
  const int G = u % NG, s = u / NG;
  const int r0 = 2 + 8 * s;
  const int gx0 = x0 - 12 + 4 * G;
  uint32_t colm = 0;
#pragma unroll
  for (int j = 0; j < 4; ++j)
    if ((unsigned)(gx0 + j) < (unsigned)W) colm |= 1u << j;
  const int p = 4 * G - 2;
  const int pw = (p < 0) ? 0 : (p >> 5);
  const int psh = (p < 0) ? 0 : (p & 31);
  const int pls = (p < 0) ? -p : 0;
  uint32_t ring[5];
#pragma unroll
  for (int k = 0; k < 12; ++k) {
    const int rr = r0 - 2 + k;
    const uint32_t* srow = MIN_ + rr * MW4;
    uint64_t X = (uint64_t)srow[pw] | ((uint64_t)srow[pw + 1] << 32);
    uint64_t win = pls ? (X << pls) : (X >> psh);
    uint64_t t = win | (win >> 1) | (win >> 2) | (win >> 3) | (win >> 4);
    ring[k % 5] = (uint32_t)t & 0xFu;
    if (k >= 4) {
      const int rq = r0 + k - 4;
      const int gy = y0 - 12 + rq;
      uint32_t nib = ring[0] | ring[1] | ring[2] | ring[3] | ring[4];
      nib &= ((unsigned)gy < (unsigned)H) ? colm : 0u;
      if (nib) atomicOr(&SOUT[rq * MW4 + (G >> 3)], nib << (4 * (G & 7)));
    }
  }
}

// ---------------- fused 5-pass NMS + candidate emit ----------------------------------
__global__ void __launch_bounds__(256, 4) k_nms(const float* __restrict__ scores,
                                                uint64_t* __restrict__ cand,
                                                uint32_t* __restrict__ cand_count) {
  __shared__ float S[RROWS * STR];
  __shared__ uint32_t MAs[RROWS * MW4];
  __shared__ uint32_t SP1[RROWS * MW4];
  __shared__ uint32_t SP2[RROWS * MW4];
  __shared__ uint64_t list[LIST_CAP];
  __shared__ uint32_t cnt_loc, base_g;
  const int b = blockIdx.z;
  const int x0 = blockIdx.x * 64, y0 = blockIdx.y * 64;
  const int tid = threadIdx.x;
  const float* img = scores + (size_t)b * H * W;
  if (tid == 0) cnt_loc = 0;

  for (int u = tid; u < RROWS * NG; u += 256) {
    int r = u / NG, G = u % NG;
    int gy = y0 - 12 + r, gx = x0 - 12 + 4 * G;
    float4 v;
    if ((unsigned)gy < (unsigned)H && (unsigned)gx < (unsigned)W)
      v = ld4(img + (size_t)gy * W + gx);
    else
      v = make_float4(-INFINITY, -INFINITY, -INFINITY, -INFINITY);
    *reinterpret_cast<float4*>(&S[r * STR + 4 * G]) = v;
  }
  for (int i = tid; i < RROWS * MW4; i += 256) {
    MAs[i] = 0;
    SP1[i] = 0;
    SP2[i] = 0;
  }
  __syncthreads();
  if (tid < NUNIT)
    score_pass<0>(tid, x0, y0, S, nullptr, MAs, nullptr, nullptr, nullptr, nullptr, b);
  __syncthreads();
  if (tid < NUNIT) dilate_pass(tid, x0, y0, MAs, SP1);
  __syncthreads();
  if (tid < NUNIT)
    score_pass<1>(tid, x0, y0, S, SP1, MAs, nullptr, nullptr, nullptr, nullptr, b);
  __syncthreads();
  if (tid < NUNIT) dilate_pass(tid, x0, y0, MAs, SP2);
  __syncthreads();
  if (tid < NUNIT)
    score_pass<2>(tid, x0, y0, S, SP2, MAs, list, &cnt_loc, cand, cand_count, b);
  __syncthreads();
  uint32_t nblk = cnt_loc;
  uint32_t nmain = nblk < (uint32_t)LIST_CAP ? nblk : (uint32_t)LIST_CAP;
  if (tid == 0) base_g = atomicAdd(&cand_count[b], nmain);
  __syncthreads();
  uint32_t bg = base_g;
  for (uint32_t i = tid; i < nmain; i += 256) {
    uint32_t pp = bg + i;
    if (pp < (uint32_t)CAND_CAP) cand[(size_t)b * CAND_CAP + pp] = list[i];
  }
}

// ---------------- two-level radix threshold ------------------------------------------
__global__ void __launch_bounds__(1024) k_select(const uint64_t* __restrict__ cand,
                                                 const uint32_t* __restrict__ cand_count,
                                                 uint64_t* __restrict__ thr_key) {
  __shared__ uint32_t h1[1024];
  __shared__ uint32_t h2[4096];
  __shared__ uint32_t shC;
  __shared__ uint32_t sh_above;
  const int b = blockIdx.x;
  const int t = threadIdx.x;
  uint32_t n = cand_count[b];
  if (n > (uint32_t)CAND_CAP) n = CAND_CAP;
  const uint64_t* cb = cand + (size_t)b * CAND_CAP;

  h1[t] = 0;
  if (t == 0) { shC = 0xFFFFFFFFu; sh_above = 0; }
  __syncthreads();
  for (uint32_t i = t; i < n; i += 1024) atomicAdd(&h1[(uint32_t)(cb[i] >> 54)], 1u);
  __syncthreads();
  for (int d = 1; d < 1024; d <<= 1) {
    uint32_t v = (t + d < 1024) ? h1[t + d] : 0u;
    __syncthreads();
    h1[t] += v;
    __syncthreads();
  }
  if (h1[0] < (uint32_t)TOPK) {
    if (t == 0) thr_key[b] = 0ull;
    return;
  }
  {
    uint32_t mine = h1[t];
    uint32_t nxt = (t + 1 < 1024) ? h1[t + 1] : 0u;
    if (mine >= (uint32_t)TOPK && nxt < (uint32_t)TOPK) { shC = (uint32_t)t; sh_above = nxt; }
  }
  __syncthreads();
  const uint32_t C = shC;
  const uint32_t above = sh_above;
#pragma unroll
  for (int j = 0; j < 4; ++j) h2[t + j * 1024] = 0;
  __syncthreads();
  for (uint32_t i = t; i < n; i += 1024) {
    uint64_t key = cb[i];
    if ((uint32_t)(key >> 54) == C) atomicAdd(&h2[(uint32_t)(key >> 42) & 0xFFFu], 1u);
  }
  __syncthreads();
  for (int d = 1; d < 4096; d <<= 1) {
    uint32_t v[4];
#pragma unroll
    for (int j = 0; j < 4; ++j) {
      int i = t + j * 1024;
      v[j] = (i + d < 4096) ? h2[i + d] : 0u;
    }
    __syncthreads();
#pragma unroll
    for (int j = 0; j < 4; ++j) h2[t + j * 1024] += v[j];
    __syncthreads();
  }
#pragma unroll
  for (int j = 0; j < 4; ++j) {
    int f = t + j * 1024;
    uint32_t cum = above + h2[f];
    uint32_t cumn = (f + 1 < 4096) ? above + h2[f + 1] : above;
    if (cum >= (uint32_t)TOPK && cumn < (uint32_t)TOPK)
      thr_key[b] = ((uint64_t)C << 54) | ((uint64_t)f << 42);
  }
}

// ---------------- compact ------------------------------------------------------------
__global__ void __launch_bounds__(1024) k_compact(const uint64_t* __restrict__ cand,
                                                  const uint32_t* __restrict__ cand_count,
                                                  const uint64_t* __restrict__ thr_key,
                                                  uint64_t* __restrict__ sel,
                                                  uint32_t* __restrict__ sel_count) {
  __shared__ uint64_t list[1024];
  __shared__ uint32_t cnt_loc;
  __shared__ uint32_t base_g;
  const int b = blockIdx.y;
  uint32_t n = cand_count[b];
  if (n > (uint32_t)CAND_CAP) n = CAND_CAP;
  const int tid = threadIdx.x;
  if (tid == 0) cnt_loc = 0;
  __syncthreads();
  uint32_t i = blockIdx.x * 1024 + tid;
  if (i < n) {
    uint64_t key = cand[(size_t)b * CAND_CAP + i];
    if (key >= thr_key[b]) {
      uint32_t pos = atomicAdd(&cnt_loc, 1u);
      list[pos] = key;
    }
  }
  __syncthreads();
  uint32_t nblk = cnt_loc;
  if (tid == 0 && nblk > 0) base_g = atomicAdd(&sel_count[b], nblk);
  __syncthreads();
  if (nblk > 0 && (uint32_t)tid < nblk) {
    uint32_t pp = base_g + tid;
    if (pp < (uint32_t)SEL_CAP) sel[(size_t)b * SEL_CAP + pp] = list[tid];
  }
}

// ---------------- tiled partial ranking ----------------------------------------------
// rank[me] = #{keys > me} over all n selected keys, accumulated per 1024-key chunk.
// Keys are distinct => ranks form a permutation => exact JAX top_k order.
__global__ void __launch_bounds__(RK_ME) k_rank_part(const uint64_t* __restrict__ sel,
                                                     const uint32_t* __restrict__ sel_count,
                                                     uint32_t* __restrict__ rankg) {
  __shared__ uint64_t keys[RK_CH];  // 8 KiB
  const int b = blockIdx.z;
  uint32_t n = sel_count[b];
  if (n > (uint32_t)SEL_CAP) n = SEL_CAP;
  const uint32_t me0 = blockIdx.x * RK_ME;
  const uint32_t c0 = blockIdx.y * RK_CH;
  if (me0 >= n || c0 >= n) return;
  const uint64_t* sb = sel + (size_t)b * SEL_CAP;
  uint32_t clen = n - c0;
  if (clen > (uint32_t)RK_CH) clen = RK_CH;
  for (uint32_t i = threadIdx.x; i < clen; i += RK_ME) keys[i] = sb[c0 + i];
  __syncthreads();
  const uint32_t me = me0 + threadIdx.x;
  if (me >= n) return;
  const uint64_t kme = sb[me];
  uint32_t rank = 0;
  uint32_t i = 0;
  for (; i + 8 <= clen; i += 8) {
    rank += (keys[i] > kme);
    rank += (keys[i + 1] > kme);
    rank += (keys[i + 2] > kme);
    rank += (keys[i + 3] > kme);
    rank += (keys[i + 4] > kme);
    rank += (keys[i + 5] > kme);
    rank += (keys[i + 6] > kme);
    rank += (keys[i + 7] > kme);
  }
  for (; i < clen; ++i) rank += (keys[i] > kme);
  if (rank) atomicAdd(&rankg[(size_t)b * SEL_CAP + me], rank);
}

// scatter: topk[rank[i]] = sel[i] for rank < TOPK
__global__ void __launch_bounds__(256) k_scatter(const uint64_t* __restrict__ sel,
                                                 const uint32_t* __restrict__ sel_count,
                                                 const uint32_t* __restrict__ rankg,
                                                 uint64_t* __restrict__ topk) {
  const int b = blockIdx.y;
  uint32_t n = sel_count[b];
  if (n > (uint32_t)SEL_CAP) n = SEL_CAP;
  uint32_t i = blockIdx.x * 256 + threadIdx.x;
  if (i >= n) return;
  uint32_t r = rankg[(size_t)b * SEL_CAP + i];
  if (r < (uint32_t)TOPK) topk[(size_t)b * TOPK + r] = sel[(size_t)b * SEL_CAP + i];
}

// ---------------- refinement: 8 lanes per keypoint -----------------------------------
__global__ void __launch_bounds__(256) k_refine(const float* __restrict__ scores,
                                                const uint64_t* __restrict__ topk,
                                                float* __restrict__ out) {
  int gid = blockIdx.x * 256 + threadIdx.x;
  int kp = gid >> 3, ln = gid & 7;
  const int b = kp / TOPK;
  const int k = kp % TOPK;
  uint64_t key = topk[(size_t)b * TOPK + k];
  uint32_t flat = 0xFFFFFFFFu - (uint32_t)(key & 0xFFFFFFFFull);
  if (flat >= (uint32_t)(H * W)) flat = 0;  // pad-key guard
  const int ix = (int)(flat % W);
  const int iy = (int)(flat / W);
  const float* img = scores + (size_t)b * H * W;

  const int nt = (ln == 0) ? 4 : 3;
  float v[4];
  float mymax = -INFINITY;
#pragma unroll
  for (int i = 0; i < 4; ++i) {
    if (i < nt) {
      int t = ln + 8 * i;
      int y = iy + t / 5 - 2, x = ix + t % 5 - 2;
      float val = ((unsigned)x < (unsigned)W && (unsigned)y < (unsigned)H)
                      ? img[(size_t)y * W + x] : 0.0f;
      v[i] = val;
      mymax = fmaxf(mymax, val);
    }
  }
#pragma unroll
  for (int m = 1; m < 8; m <<= 1) mymax = fmaxf(mymax, __shfl_xor(mymax, m));
  float e[4];
  float sum = 0.f, sx = 0.f, sy = 0.f;
#pragma unroll
  for (int i = 0; i < 4; ++i) {
    if (i < nt) {
      int t = ln + 8 * i;
      float ev = expf((v[i] - mymax) / 0.1f);
      e[i] = ev;
      sum += ev;
      sx += ev * (float)(t % 5 - 2);
      sy += ev * (float)(t / 5 - 2);
    }
  }
#pragma unroll
  for (int m = 1; m < 8; m <<= 1) {
    sum += __shfl_xor(sum, m);
    sx += __shfl_xor(sx, m);
    sy += __shfl_xor(sy, m);
  }
  float rx = sx / sum, ry = sy / sum;
  float dsp = 0.f;
#pragma unroll
  for (int i = 0; i < 4; ++i) {
    if (i < nt) {
      int t = ln + 8 * i;
      float dx = ((float)(t % 5 - 2) - rx) * 0.5f;
      float dy = ((float)(t / 5 - 2) - ry) * 0.5f;
      dsp += e[i] * (dx * dx + dy * dy);
    }
  }
#pragma unroll
  for (int m = 1; m < 8; m <<= 1) dsp += __shfl_xor(dsp, m);
  if (ln != 0) return;
  dsp /= sum;
  float kx = ((float)ix + rx) / 1023.0f * 2.0f - 1.0f;
  float ky = ((float)iy + ry) / 1023.0f * 2.0f - 1.0f;
  float px = (kx + 1.0f) * 0.5f * 1023.0f;
  float py = (ky + 1.0f) * 0.5f * 1023.0f;
  float x0f = floorf(px), y0f = floorf(py);
  float wx1 = px - x0f, wx0 = 1.0f - wx1;
  float wy1 = py - y0f, wy0 = 1.0f - wy1;
  int x0 = (int)x0f, y0 = (int)y0f;
  float sc = 0.0f;
  {
    int xs[2] = {x0, x0 + 1};
    int ys[2] = {y0, y0 + 1};
    float wxs[2] = {wx0, wx1};
    float wys[2] = {wy0, wy1};
#pragma unroll
    for (int yy = 0; yy < 2; ++yy)
#pragma unroll
      for (int xx = 0; xx < 2; ++xx) {
        int xi = xs[xx], yi = ys[yy];
        bool valid = (xi >= 0 && xi < W && yi >= 0 && yi < H);
        int xc = min(max(xi, 0), W - 1);
        int yc = min(max(yi, 0), H - 1);
        float vv = valid ? img[(size_t)yc * W + xc] : 0.0f;
        sc += vv * (wxs[xx] * wys[yy]);
      }
  }
  out[((size_t)b * TOPK + k) * 2 + 0] = kx;
  out[((size_t)b * TOPK + k) * 2 + 1] = ky;
  out[(size_t)B * TOPK * 2 + (size_t)b * TOPK + k] = sc;
  out[(size_t)B * TOPK * 3 + (size_t)b * TOPK + k] = dsp;
}

}  // namespace

extern "C" void kernel_launch(void* const* d_in, const int* in_sizes, int n_in,
                              void* d_out, int out_size, void* d_ws, size_t ws_size,
                              hipStream_t stream) {
  const float* scores = (const float*)d_in[0];
  float* out = (float*)d_out;
  char* ws = (char*)d_ws;

  uint32_t* cnt = (uint32_t*)(ws + OFF_CNT);
  uint32_t* cand_count = cnt;                    // [B]
  uint32_t* sel_count  = cnt + 8;                // [B]
  uint64_t* thr_key    = (uint64_t*)(cnt + 16);  // [B]
  uint32_t* rankg = (uint32_t*)(ws + OFF_RANK);
  uint64_t* sel  = (uint64_t*)(ws + OFF_SEL);
  uint64_t* topk = (uint64_t*)(ws + OFF_TOPK);
  uint64_t* cand = (uint64_t*)(ws + OFF_CAND);

  hipMemsetAsync(ws + OFF_CNT, 0, MEMSET_BYTES, stream);

  k_nms<<<dim3(W / 64, H / 64, B), 256, 0, stream>>>(scores, cand, cand_count);
  k_select<<<B, 1024, 0, stream>>>(cand, cand_count, thr_key);
  k_compact<<<dim3(CAND_CAP / 1024, B), 1024, 0, stream>>>(cand, cand_count, thr_key, sel, sel_count);
  k_rank_part<<<dim3(SEL_CAP / RK_ME, SEL_CAP / RK_CH, B), RK_ME, 0, stream>>>(sel, sel_count, rankg);
  k_scatter<<<dim3(SEL_CAP / 256, B), 256, 0, stream>>>(sel, sel_count, rankg, topk);
  k_refine<<<(B * TOPK * 8) / 256, 256, 0, stream>>>(scores, topk, out);
}

// Round 7
// 224.906 us; speedup vs baseline: 9.3624x; 1.1508x over previous
//
#include <hip/hip_runtime.h>
#include <stdint.h>

namespace {

constexpr int B = 8;
constexpr int H = 1024;
constexpr int W = 1024;
constexpr int TOPK = 4096;
constexpr int CAND_CAP = 131072;  // per batch
constexpr int SEL_CAP = 16384;    // per batch (overselect ~2k above TOPK; big margin)
constexpr int LIST_CAP = 320;     // per 64x64 tile (avg ~164 survivors; fallback below)
constexpr int HIST_N = 32768;     // 17-bit key prefix = score_bits>>15 (max 32512)
constexpr int NCHUNK = 32;        // 32 chunks x 1024 buckets
constexpr int NHB = 48;           // hist slice blocks per batch

// fused-NMS tile: 64x64 interior, radius-12 staged halo. Staged rows padded to 92
// (strips write rows 2..89; garbage from pad rows >=88 shrinks 2/stage: mask0>=86,
// supp1>=84, mask1>=82, supp2>=80, final>=78 — interior rows 12..75 untouched).
constexpr int RROWS = 92;   // staged score rows
constexpr int NG = 22;      // float4 col-groups (88 cols)
constexpr int STR = 88;     // score row stride (floats; 352B, 16B-aligned rows)
constexpr int MW4 = 4;      // bitpacked mask words per row (96 bits; word 3 = zero pad)
constexpr int NSTRIP = 11;  // 11 strips x 8 output rows = rows 2..89
constexpr int NUNIT = NG * NSTRIP;  // 242 <= 256: one round per pass, no tail

// rank kernel tiling
constexpr int RK_ME = 256;    // me-keys per block (1/thread)
constexpr int RK_CH = 1024;   // chunk keys staged in LDS per block

// workspace layout (bytes). cnt page also holds gchunk (at +1024).
constexpr size_t OFF_CNT   = 0;                                    // 4 KiB
constexpr size_t OFF_GHIST = 4096;                                 // B*HIST_N*4 = 1 MiB
constexpr size_t OFF_RANK  = OFF_GHIST + (size_t)B * HIST_N * 4;   // B*SEL_CAP*4 = 512 KiB
constexpr size_t OFF_SEL   = OFF_RANK + (size_t)B * SEL_CAP * 4;   // B*SEL_CAP*8 = 1 MiB
constexpr size_t OFF_TOPK  = OFF_SEL + (size_t)B * SEL_CAP * 8;    // 256 KiB
constexpr size_t OFF_CAND  = OFF_TOPK + (size_t)B * TOPK * 8;      // 8 MiB
constexpr size_t MEMSET_BYTES = OFF_RANK + (size_t)B * SEL_CAP * 4;  // cnt+ghist+rank

__device__ __forceinline__ float max5(float a, float b, float c, float d, float e) {
  return fmaxf(fmaxf(fmaxf(a, b), fmaxf(c, d)), e);
}
__device__ __forceinline__ float4 ld4(const float* p) {
  return *reinterpret_cast<const float4*>(p);
}

// One unit: col-group G in [0,22), strip s in [0,11) -> staged rows r0..r0+7 (r0=2+8s).
// Sliding 5-row window of horizontal 5-maxes in registers. Masks bitpacked 1bit/px.
template <int PASS>
__device__ __forceinline__ void score_pass(
    int u, int x0, int y0, const float* __restrict__ S,
    const uint32_t* __restrict__ SUP, uint32_t* __restrict__ MA,
    uint64_t* list, uint32_t* cnt_loc, uint64_t* cand, uint32_t* cand_count, int b) {
  const int G = u % NG, s = u / NG;
  const int r0 = 2 + 8 * s;
  const int gx0 = x0 - 12 + 4 * G;
  uint32_t colm = 0;
#pragma unroll
  for (int j = 0; j < 4; ++j)
    if ((unsigned)(gx0 + j) < (unsigned)W) colm |= 1u << j;
  const int p = 4 * G - 4;
  const int pw = (p < 0) ? 0 : (p >> 5);
  const int psh = (p < 0) ? 0 : (p & 31);
  const int pls = (p < 0) ? -p : 0;

  float4 hw[5], cw[5];
  uint32_t sn[5];
#pragma unroll
  for (int k = 0; k < 12; ++k) {
    const int rr = r0 - 2 + k;
    const float* rowp = S + rr * STR + 4 * G;
    float4 d = ld4(rowp);
    float4 a = (G > 0) ? ld4(rowp - 4) : d;  // garbage-only cols, safe
    float4 e = (G < NG - 1) ? ld4(rowp + 4) : d;
    uint32_t supn = 0;
    if (PASS != 0) {
      const uint32_t* srow = SUP + rr * MW4;
      uint64_t X = (uint64_t)srow[pw] | ((uint64_t)srow[pw + 1] << 32);
      uint64_t win = pls ? (X << pls) : (X >> psh);
      if (win & 0x001u) a.x = 0.f;
      if (win & 0x002u) a.y = 0.f;
      if (win & 0x004u) a.z = 0.f;
      if (win & 0x008u) a.w = 0.f;
      if (win & 0x010u) d.x = 0.f;
      if (win & 0x020u) d.y = 0.f;
      if (win & 0x040u) d.z = 0.f;
      if (win & 0x080u) d.w = 0.f;
      if (win & 0x100u) e.x = 0.f;
      if (win & 0x200u) e.y = 0.f;
      if (win & 0x400u) e.z = 0.f;
      if (win & 0x800u) e.w = 0.f;
      supn = (uint32_t)(win >> 4) & 0xFu;
    }
    float4 hm;
    hm.x = max5(a.z, a.w, d.x, d.y, d.z);
    hm.y = max5(a.w, d.x, d.y, d.z, d.w);
    hm.z = max5(d.x, d.y, d.z, d.w, e.x);
    hm.w = max5(d.y, d.z, d.w, e.x, e.y);
    hw[k % 5] = hm;
    cw[k % 5] = d;
    sn[k % 5] = supn;
    if (k >= 4) {
      const int rq = r0 + k - 4;
      const int gy = y0 - 12 + rq;
      float4 vm;
      vm.x = max5(hw[0].x, hw[1].x, hw[2].x, hw[3].x, hw[4].x);
      vm.y = max5(hw[0].y, hw[1].y, hw[2].y, hw[3].y, hw[4].y);
      vm.z = max5(hw[0].z, hw[1].z, hw[2].z, hw[3].z, hw[4].z);
      vm.w = max5(hw[0].w, hw[1].w, hw[2].w, hw[3].w, hw[4].w);
      float4 c = cw[(k + 3) % 5];  // center row rq (masked value for PASS 1/2)
      uint32_t nm = (uint32_t)(c.x == vm.x) | ((uint32_t)(c.y == vm.y) << 1) |
                    ((uint32_t)(c.z == vm.z) << 2) | ((uint32_t)(c.w == vm.w) << 3);
      nm &= ((unsigned)gy < (unsigned)H) ? colm : 0u;
      const int widx = rq * MW4 + (G >> 3);
      const int shift = 4 * (G & 7);
      if (PASS == 0) {
        if (nm) atomicOr(&MA[widx], nm << shift);
      } else if (PASS == 1) {
        uint32_t v = nm & ~sn[(k + 3) % 5];
        if (v) atomicOr(&MA[widx], v << shift);
      } else {
        uint32_t fin = ((MA[widx] >> shift) & 0xFu) | (nm & ~sn[(k + 3) % 5]);
        if (fin && G >= 3 && G < 19 && rq >= 12 && rq < 76 && gy >= 2 && gy < H - 2) {
#pragma unroll
          for (int j = 0; j < 4; ++j) {
            if ((fin >> j) & 1u) {
              int gx = gx0 + j;
              if (gx >= 2 && gx < W - 2) {
                float sval = S[rq * STR + 4 * G + j];  // original (unmasked) score
                if (sval > 0.0f) {
                  uint32_t bits = __float_as_uint(sval);
                  uint32_t flat = (uint32_t)(gy * W + gx);
                  uint64_t key = ((uint64_t)bits << 32) | (uint64_t)(0xFFFFFFFFu - flat);
                  uint32_t pos = atomicAdd(cnt_loc, 1u);
                  if (pos < (uint32_t)LIST_CAP) {
                    list[pos] = key;
                  } else {  // tie overflow: direct global append (rare)
                    uint32_t pp = atomicAdd(&cand_count[b], 1u);
                    if (pp < (uint32_t)CAND_CAP) cand[(size_t)b * CAND_CAP + pp] = key;
                  }
                }
              }
            }
          }
        }
      }
    }
  }
}

// bit-dilate r=2: SOUT |= any(MIN in 5x5) & valid (nibble per (row, G))
__device__ __forceinline__ void dilate_pass(int u, int x0, int y0,
                                            const uint32_t* __restrict__ MIN_,
                                            uint32_t* __restrict__ SOUT) {
  const int G = u % NG, s = u / NG;
  const int r0 = 2 + 8 * s;
  const int gx0 = x0 - 12 + 4 * G;
  uint32_t colm = 0;
#pragma unroll
  for (int j = 0; j < 4; ++j)
    if ((unsigned)(gx0 + j) < (unsigned)W) colm |= 1u << j;
  const int p = 4 * G - 2;
  const int pw = (p < 0) ? 0 : (p >> 5);
  const int psh = (p < 0) ? 0 : (p & 31);
  const int pls = (p < 0) ? -p : 0;
  uint32_t ring[5];
#pragma unroll
  for (int k = 0; k < 12; ++k) {
    const int rr = r0 - 2 + k;
    const uint32_t* srow = MIN_ + rr * MW4;
    uint64_t X = (uint64_t)srow[pw] | ((uint64_t)srow[pw + 1] << 32);
    uint64_t win = pls ? (X << pls) : (X >> psh);
    uint64_t t = win | (win >> 1) | (win >> 2) | (win >> 3) | (win >> 4);
    ring[k % 5] = (uint32_t)t & 0xFu;
    if (k >= 4) {
      const int rq = r0 + k - 4;
      const int gy = y0 - 12 + rq;
      uint32_t nib = ring[0] | ring[1] | ring[2] | ring[3] | ring[4];
      nib &= ((unsigned)gy < (unsigned)H) ? colm : 0u;
      if (nib) atomicOr(&SOUT[rq * MW4 + (G >> 3)], nib << (4 * (G & 7)));
    }
  }
}

// ---------------- fused 5-pass NMS + candidate emit ----------------------------------
__global__ void __launch_bounds__(256, 4) k_nms(const float* __restrict__ scores,
                                                uint64_t* __restrict__ cand,
                                                uint32_t* __restrict__ cand_count) {
  __shared__ float S[RROWS * STR];
  __shared__ uint32_t MAs[RROWS * MW4];
  __shared__ uint32_t SP1[RROWS * MW4];
  __shared__ uint32_t SP2[RROWS * MW4];
  __shared__ uint64_t list[LIST_CAP];
  __shared__ uint32_t cnt_loc, base_g;
  const int b = blockIdx.z;
  const int x0 = blockIdx.x * 64, y0 = blockIdx.y * 64;
  const int tid = threadIdx.x;
  const float* img = scores + (size_t)b * H * W;
  if (tid == 0) cnt_loc = 0;

  for (int u = tid; u < RROWS * NG; u += 256) {
    int r = u / NG, G = u % NG;
    int gy = y0 - 12 + r, gx = x0 - 12 + 4 * G;
    float4 v;
    if ((unsigned)gy < (unsigned)H && (unsigned)gx < (unsigned)W)
      v = ld4(img + (size_t)gy * W + gx);
    else
      v = make_float4(-INFINITY, -INFINITY, -INFINITY, -INFINITY);
    *reinterpret_cast<float4*>(&S[r * STR + 4 * G]) = v;
  }
  for (int i = tid; i < RROWS * MW4; i += 256) {
    MAs[i] = 0;
    SP1[i] = 0;
    SP2[i] = 0;
  }
  __syncthreads();
  if (tid < NUNIT)
    score_pass<0>(tid, x0, y0, S, nullptr, MAs, nullptr, nullptr, nullptr, nullptr, b);
  __syncthreads();
  if (tid < NUNIT) dilate_pass(tid, x0, y0, MAs, SP1);
  __syncthreads();
  if (tid < NUNIT)
    score_pass<1>(tid, x0, y0, S, SP1, MAs, nullptr, nullptr, nullptr, nullptr, b);
  __syncthreads();
  if (tid < NUNIT) dilate_pass(tid, x0, y0, MAs, SP2);
  __syncthreads();
  if (tid < NUNIT)
    score_pass<2>(tid, x0, y0, S, SP2, MAs, list, &cnt_loc, cand, cand_count, b);
  __syncthreads();
  uint32_t nblk = cnt_loc;
  uint32_t nmain = nblk < (uint32_t)LIST_CAP ? nblk : (uint32_t)LIST_CAP;
  if (tid == 0) base_g = atomicAdd(&cand_count[b], nmain);
  __syncthreads();
  uint32_t bg = base_g;
  for (uint32_t i = tid; i < nmain; i += 256) {
    uint32_t pp = bg + i;
    if (pp < (uint32_t)CAND_CAP) cand[(size_t)b * CAND_CAP + pp] = list[i];
  }
}

// ---------------- grid-parallel 17-bit histogram with wave match-any -----------------
__global__ void __launch_bounds__(256) k_hist(const uint64_t* __restrict__ cand,
                                              const uint32_t* __restrict__ cand_count,
                                              uint32_t* __restrict__ ghist) {
  const int b = blockIdx.y;
  uint32_t n = cand_count[b];
  if (n > (uint32_t)CAND_CAP) n = CAND_CAP;
  uint32_t* gh = ghist + (size_t)b * HIST_N;
  const uint64_t* cb = cand + (size_t)b * CAND_CAP;
  const int lane = threadIdx.x & 63;
  for (uint32_t i = blockIdx.x * 256 + threadIdx.x;; i += NHB * 256) {
    bool valid = i < n;
    uint64_t act = __ballot(valid);
    if (!act) break;
    uint32_t bkt = 0;
    if (valid) bkt = (uint32_t)(cb[i] >> 47);  // = score_bits >> 15, < 32768
    uint64_t peers = act;
#pragma unroll
    for (int bit = 0; bit < 15; ++bit) {
      uint64_t bb = __ballot((bkt >> bit) & 1u);
      peers &= ((bkt >> bit) & 1u) ? bb : ~bb;
    }
    if (valid && (__ffsll((unsigned long long)peers) - 1) == lane)
      atomicAdd(&gh[bkt], (uint32_t)__popcll((unsigned long long)peers));
  }
}

// chunk sums: one block per (chunk, batch)
__global__ void __launch_bounds__(256) k_chunksum(const uint32_t* __restrict__ ghist,
                                                  uint32_t* __restrict__ gchunk) {
  const int b = blockIdx.y, c = blockIdx.x;
  const uint32_t* gh = ghist + (size_t)b * HIST_N + c * 1024;
  uint32_t s = 0;
#pragma unroll
  for (int j = 0; j < 4; ++j) s += gh[threadIdx.x + 256 * j];
#pragma unroll
  for (int m = 1; m < 64; m <<= 1) s += __shfl_xor(s, m);
  __shared__ uint32_t red[4];
  if ((threadIdx.x & 63) == 0) red[threadIdx.x >> 6] = s;
  __syncthreads();
  if (threadIdx.x == 0) gchunk[b * NCHUNK + c] = red[0] + red[1] + red[2] + red[3];
}

// find threshold bucket: suffix over chunks, then block-scan the crossing chunk
__global__ void __launch_bounds__(1024) k_findthr(const uint32_t* __restrict__ ghist,
                                                  const uint32_t* __restrict__ gchunk,
                                                  uint64_t* __restrict__ thr_key) {
  __shared__ uint32_t ch[NCHUNK];
  __shared__ uint32_t h[1024];
  __shared__ int shCC;
  __shared__ uint32_t sh_above;
  const int b = blockIdx.x, t = threadIdx.x;
  if (t < NCHUNK) ch[t] = gchunk[b * NCHUNK + t];
  __syncthreads();
  if (t == 0) {
    uint32_t run = 0;
    int CC = -1;
    uint32_t above = 0;
    for (int c = NCHUNK - 1; c >= 0; --c) {
      uint32_t nrun = run + ch[c];
      if (run < (uint32_t)TOPK && nrun >= (uint32_t)TOPK) { CC = c; above = run; }
      run = nrun;
    }
    if (run < (uint32_t)TOPK) CC = -1;  // fewer than TOPK candidates: select all
    shCC = CC;
    sh_above = above;
  }
  __syncthreads();
  const int CC = shCC;
  if (CC < 0) {
    if (t == 0) thr_key[b] = 0ull;
    return;
  }
  const uint32_t above = sh_above;
  h[t] = ghist[(size_t)b * HIST_N + CC * 1024 + t];
  __syncthreads();
  for (int d = 1; d < 1024; d <<= 1) {
    uint32_t v = (t + d < 1024) ? h[t + d] : 0u;
    __syncthreads();
    h[t] += v;
    __syncthreads();
  }
  uint32_t cum = above + h[t];
  uint32_t cumn = (t + 1 < 1024) ? above + h[t + 1] : above;
  if (cum >= (uint32_t)TOPK && cumn < (uint32_t)TOPK)
    thr_key[b] = (uint64_t)(CC * 1024 + t) << 47;
}

// ---------------- compact ------------------------------------------------------------
__global__ void __launch_bounds__(1024) k_compact(const uint64_t* __restrict__ cand,
                                                  const uint32_t* __restrict__ cand_count,
                                                  const uint64_t* __restrict__ thr_key,
                                                  uint64_t* __restrict__ sel,
                                                  uint32_t* __restrict__ sel_count) {
  __shared__ uint64_t list[1024];
  __shared__ uint32_t cnt_loc;
  __shared__ uint32_t base_g;
  const int b = blockIdx.y;
  uint32_t n = cand_count[b];
  if (n > (uint32_t)CAND_CAP) n = CAND_CAP;
  const int tid = threadIdx.x;
  if (tid == 0) cnt_loc = 0;
  __syncthreads();
  uint32_t i = blockIdx.x * 1024 + tid;
  if (i < n) {
    uint64_t key = cand[(size_t)b * CAND_CAP + i];
    if (key >= thr_key[b]) {
      uint32_t pos = atomicAdd(&cnt_loc, 1u);
      list[pos] = key;
    }
  }
  __syncthreads();
  uint32_t nblk = cnt_loc;
  if (tid == 0 && nblk > 0) base_g = atomicAdd(&sel_count[b], nblk);
  __syncthreads();
  if (nblk > 0 && (uint32_t)tid < nblk) {
    uint32_t pp = base_g + tid;
    if (pp < (uint32_t)SEL_CAP) sel[(size_t)b * SEL_CAP + pp] = list[tid];
  }
}

// ---------------- tiled partial ranking ----------------------------------------------
// rank[me] = #{keys > me} over all n selected keys, accumulated per 1024-key chunk.
// Keys are distinct => ranks form a permutation => exact JAX top_k order.
__global__ void __launch_bounds__(RK_ME) k_rank_part(const uint64_t* __restrict__ sel,
                                                     const uint32_t* __restrict__ sel_count,
                                                     uint32_t* __restrict__ rankg) {
  __shared__ uint64_t keys[RK_CH];  // 8 KiB
  const int b = blockIdx.z;
  uint32_t n = sel_count[b];
  if (n > (uint32_t)SEL_CAP) n = SEL_CAP;
  const uint32_t me0 = blockIdx.x * RK_ME;
  const uint32_t c0 = blockIdx.y * RK_CH;
  if (me0 >= n || c0 >= n) return;
  const uint64_t* sb = sel + (size_t)b * SEL_CAP;
  uint32_t clen = n - c0;
  if (clen > (uint32_t)RK_CH) clen = RK_CH;
  for (uint32_t i = threadIdx.x; i < clen; i += RK_ME) keys[i] = sb[c0 + i];
  __syncthreads();
  const uint32_t me = me0 + threadIdx.x;
  if (me >= n) return;
  const uint64_t kme = sb[me];
  uint32_t rank = 0;
  uint32_t i = 0;
  for (; i + 8 <= clen; i += 8) {
    rank += (keys[i] > kme);
    rank += (keys[i + 1] > kme);
    rank += (keys[i + 2] > kme);
    rank += (keys[i + 3] > kme);
    rank += (keys[i + 4] > kme);
    rank += (keys[i + 5] > kme);
    rank += (keys[i + 6] > kme);
    rank += (keys[i + 7] > kme);
  }
  for (; i < clen; ++i) rank += (keys[i] > kme);
  if (rank) atomicAdd(&rankg[(size_t)b * SEL_CAP + me], rank);
}

// scatter: topk[rank[i]] = sel[i] for rank < TOPK
__global__ void __launch_bounds__(256) k_scatter(const uint64_t* __restrict__ sel,
                                                 const uint32_t* __restrict__ sel_count,
                                                 const uint32_t* __restrict__ rankg,
                                                 uint64_t* __restrict__ topk) {
  const int b = blockIdx.y;
  uint32_t n = sel_count[b];
  if (n > (uint32_t)SEL_CAP) n = SEL_CAP;
  uint32_t i = blockIdx.x * 256 + threadIdx.x;
  if (i >= n) return;
  uint32_t r = rankg[(size_t)b * SEL_CAP + i];
  if (r < (uint32_t)TOPK) topk[(size_t)b * TOPK + r] = sel[(size_t)b * SEL_CAP + i];
}

// ---------------- refinement: 8 lanes per keypoint -----------------------------------
__global__ void __launch_bounds__(256) k_refine(const float* __restrict__ scores,
                                                const uint64_t* __restrict__ topk,
                                                float* __restrict__ out) {
  int gid = blockIdx.x * 256 + threadIdx.x;
  int kp = gid >> 3, ln = gid & 7;
  const int b = kp / TOPK;
  const int k = kp % TOPK;
  uint64_t key = topk[(size_t)b * TOPK + k];
  uint32_t flat = 0xFFFFFFFFu - (uint32_t)(key & 0xFFFFFFFFull);
  if (flat >= (uint32_t)(H * W)) flat = 0;  // pad-key guard
  const int ix = (int)(flat % W);
  const int iy = (int)(flat / W);
  const float* img = scores + (size_t)b * H * W;

  const int nt = (ln == 0) ? 4 : 3;
  float v[4];
  float mymax = -INFINITY;
#pragma unroll
  for (int i = 0; i < 4; ++i) {
    if (i < nt) {
      int t = ln + 8 * i;
      int y = iy + t / 5 - 2, x = ix + t % 5 - 2;
      float val = ((unsigned)x < (unsigned)W && (unsigned)y < (unsigned)H)
                      ? img[(size_t)y * W + x] : 0.0f;
      v[i] = val;
      mymax = fmaxf(mymax, val);
    }
  }
#pragma unroll
  for (int m = 1; m < 8; m <<= 1) mymax = fmaxf(mymax, __shfl_xor(mymax, m));
  float e[4];
  float sum = 0.f, sx = 0.f, sy = 0.f;
#pragma unroll
  for (int i = 0; i < 4; ++i) {
    if (i < nt) {
      int t = ln + 8 * i;
      float ev = expf((v[i] - mymax) / 0.1f);
      e[i] = ev;
      sum += ev;
      sx += ev * (float)(t % 5 - 2);
      sy += ev * (float)(t / 5 - 2);
    }
  }
#pragma unroll
  for (int m = 1; m < 8; m <<= 1) {
    sum += __shfl_xor(sum, m);
    sx += __shfl_xor(sx, m);
    sy += __shfl_xor(sy, m);
  }
  float rx = sx / sum, ry = sy / sum;
  float dsp = 0.f;
#pragma unroll
  for (int i = 0; i < 4; ++i) {
    if (i < nt) {
      int t = ln + 8 * i;
      float dx = ((float)(t % 5 - 2) - rx) * 0.5f;
      float dy = ((float)(t / 5 - 2) - ry) * 0.5f;
      dsp += e[i] * (dx * dx + dy * dy);
    }
  }
#pragma unroll
  for (int m = 1; m < 8; m <<= 1) dsp += __shfl_xor(dsp, m);
  if (ln != 0) return;
  dsp /= sum;
  float kx = ((float)ix + rx) / 1023.0f * 2.0f - 1.0f;
  float ky = ((float)iy + ry) / 1023.0f * 2.0f - 1.0f;
  float px = (kx + 1.0f) * 0.5f * 1023.0f;
  float py = (ky + 1.0f) * 0.5f * 1023.0f;
  float x0f = floorf(px), y0f = floorf(py);
  float wx1 = px - x0f, wx0 = 1.0f - wx1;
  float wy1 = py - y0f, wy0 = 1.0f - wy1;
  int x0 = (int)x0f, y0 = (int)y0f;
  float sc = 0.0f;
  {
    int xs[2] = {x0, x0 + 1};
    int ys[2] = {y0, y0 + 1};
    float wxs[2] = {wx0, wx1};
    float wys[2] = {wy0, wy1};
#pragma unroll
    for (int yy = 0; yy < 2; ++yy)
#pragma unroll
      for (int xx = 0; xx < 2; ++xx) {
        int xi = xs[xx], yi = ys[yy];
        bool valid = (xi >= 0 && xi < W && yi >= 0 && yi < H);
        int xc = min(max(xi, 0), W - 1);
        int yc = min(max(yi, 0), H - 1);
        float vv = valid ? img[(size_t)yc * W + xc] : 0.0f;
        sc += vv * (wxs[xx] * wys[yy]);
      }
  }
  out[((size_t)b * TOPK + k) * 2 + 0] = kx;
  out[((size_t)b * TOPK + k) * 2 + 1] = ky;
  out[(size_t)B * TOPK * 2 + (size_t)b * TOPK + k] = sc;
  out[(size_t)B * TOPK * 3 + (size_t)b * TOPK + k] = dsp;
}

}  // namespace

extern "C" void kernel_launch(void* const* d_in, const int* in_sizes, int n_in,
                              void* d_out, int out_size, void* d_ws, size_t ws_size,
                              hipStream_t stream) {
  const float* scores = (const float*)d_in[0];
  float* out = (float*)d_out;
  char* ws = (char*)d_ws;

  uint32_t* cnt = (uint32_t*)(ws + OFF_CNT);
  uint32_t* cand_count = cnt;                      // [B]
  uint32_t* sel_count  = cnt + 8;                  // [B]
  uint64_t* thr_key    = (uint64_t*)(cnt + 16);    // [B] (bytes 64..128)
  uint32_t* gchunk     = cnt + 256;                // [B*NCHUNK] (bytes 1024..2048)
  uint32_t* ghist = (uint32_t*)(ws + OFF_GHIST);
  uint32_t* rankg = (uint32_t*)(ws + OFF_RANK);
  uint64_t* sel  = (uint64_t*)(ws + OFF_SEL);
  uint64_t* topk = (uint64_t*)(ws + OFF_TOPK);
  uint64_t* cand = (uint64_t*)(ws + OFF_CAND);

  hipMemsetAsync(ws + OFF_CNT, 0, MEMSET_BYTES, stream);

  k_nms<<<dim3(W / 64, H / 64, B), 256, 0, stream>>>(scores, cand, cand_count);
  k_hist<<<dim3(NHB, B), 256, 0, stream>>>(cand, cand_count, ghist);
  k_chunksum<<<dim3(NCHUNK, B), 256, 0, stream>>>(ghist, gchunk);
  k_findthr<<<B, 1024, 0, stream>>>(ghist, gchunk, thr_key);
  k_compact<<<dim3(CAND_CAP / 1024, B), 1024, 0, stream>>>(cand, cand_count, thr_key, sel, sel_count);
  k_rank_part<<<dim3(SEL_CAP / RK_ME, SEL_CAP / RK_CH, B), RK_ME, 0, stream>>>(sel, sel_count, rankg);
  k_scatter<<<dim3(SEL_CAP / 256, B), 256, 0, stream>>>(sel, sel_count, rankg, topk);
  k_refine<<<(B * TOPK * 8) / 256, 256, 0, stream>>>(scores, topk, out);
}